// Round 6
// baseline (4553.259 us; speedup 1.0000x reference)
//
#include <hip/hip_runtime.h>
#include <cstdint>
#include <cstddef>

typedef __bf16 bf16;
typedef __bf16 bf16x2 __attribute__((ext_vector_type(2)));
typedef __bf16 bf16x4 __attribute__((ext_vector_type(4)));
typedef __bf16 bf16x8 __attribute__((ext_vector_type(8)));
typedef float  f32x4  __attribute__((ext_vector_type(4)));
typedef __attribute__((address_space(1))) unsigned int u32_g;
typedef __attribute__((address_space(3))) unsigned int u32_l;

#define DI __device__ __forceinline__

constexpr int Bc = 2, Sc = 2048, Dc = 1024, Hc = 16, HDc = 64, Fc = 4096, Mc = 1024;
constexpr int NTc = Bc * Sc;  // 4096 tokens

DI void llds16(const bf16* g, bf16* l) {
  __builtin_amdgcn_global_load_lds((const u32_g*)g, (u32_l*)l, 16, 0, 0);
}
DI f32x4 cvt4(bf16x4 a) {
  f32x4 r; r[0] = (float)a[0]; r[1] = (float)a[1]; r[2] = (float)a[2]; r[3] = (float)a[3];
  return r;
}

// ---------------------------------------------------------------- dtype detector (inputs)
// flag=1 if inputs fp32, 0 if bf16.
__global__ void k_detect(const unsigned short* __restrict__ x, int* __restrict__ flag)
{
  const int tid = threadIdx.x;  // 64
  int cnt = 0;
#pragma unroll
  for (int i = 0; i < 8; i++) {
    unsigned short h = x[tid * 8 + i];
    int e = (h >> 7) & 0xFF;
    if (e < 96 || e > 160) cnt++;
  }
#pragma unroll
  for (int off = 32; off > 0; off >>= 1) cnt += __shfl_down(cnt, off, 64);
  if (tid == 0) *flag = (cnt > 32) ? 1 : 0;
}

// ---------------------------------------------------------------- dtype-aware convert to bf16
__global__ __launch_bounds__(256)
void k_cvt(const void* __restrict__ src, bf16* __restrict__ dst, int n4, const int* __restrict__ flag)
{
  int i = blockIdx.x * 256 + threadIdx.x;
  if (i >= n4) return;
  bf16x4 o;
  if (*flag) {
    f32x4 v = ((const f32x4*)src)[i];
    o[0] = (bf16)v[0]; o[1] = (bf16)v[1]; o[2] = (bf16)v[2]; o[3] = (bf16)v[3];
  } else {
    o = ((const bf16x4*)src)[i];
  }
  ((bf16x4*)dst)[i] = o;
}

// ---------------------------------------------------------------- dtype-aware transpose [R][C] -> bf16 [C][R]
__global__ void k_transpose_dt(const void* __restrict__ src, bf16* __restrict__ dst,
                               int R, int C, const int* __restrict__ flag)
{
  __shared__ bf16 tile[32][33];
  const int c0 = blockIdx.x * 32, r0 = blockIdx.y * 32;
  const int tx = threadIdx.x, ty = threadIdx.y;
  const bool f32 = (*flag != 0);
  for (int i = ty; i < 32; i += 8) {
    size_t idx = (size_t)(r0 + i) * C + (c0 + tx);
    tile[i][tx] = f32 ? (bf16)((const float*)src)[idx] : ((const bf16*)src)[idx];
  }
  __syncthreads();
  for (int i = ty; i < 32; i += 8)
    dst[(size_t)(c0 + i) * R + (r0 + tx)] = tile[tx][i];
}

// ---------------------------------------------------------------- GEMM (NT): C[M][N] = A[M][K] * Bt[N][K]^T
enum EpiMode { EPI_BF16 = 0, EPI_BIAS_BF16, EPI_BIAS_RELU_BF16, EPI_BIAS_RESB_F32,
               EPI_SILU_BF16, EPI_DZ_BF16, EPI_RESX_BF16, EPI_RESF_F32 };

template <int EPI>
__global__ __launch_bounds__(256)
void k_gemm(const bf16* __restrict__ A, const bf16* __restrict__ Bt,
            int Mr, int Nr, int Kr,
            float* outF, bf16* outB,
            const bf16* __restrict__ bias, const bf16* auxB,
            const float* resF,
            const void* __restrict__ resX, const int* __restrict__ flag)
{
  __shared__ bf16 As[128 * 32];
  __shared__ bf16 Bs[128 * 32];
  const int tid = threadIdx.x;
  const int w = tid >> 6, l = tid & 63;
  const int wr = w >> 1, wc = w & 1;
  const int row0 = blockIdx.y * 128, col0 = blockIdx.x * 128;

  const f32x4 vzero = {0.f, 0.f, 0.f, 0.f};
  f32x4 acc[4][4];
#pragma unroll
  for (int i = 0; i < 4; i++)
#pragma unroll
    for (int j = 0; j < 4; j++) acc[i][j] = vzero;

  const bf16* Ag = A + (size_t)(row0 + w * 16 + (l >> 2)) * Kr + ((l & 3) << 3);
  const bf16* Bg = Bt + (size_t)(col0 + w * 16 + (l >> 2)) * Kr + ((l & 3) << 3);
  bf16* AsW = &As[w * 512];
  bf16* BsW = &Bs[w * 512];
  const size_t rowHop = (size_t)64 * Kr;

  for (int k0 = 0; k0 < Kr; k0 += 32) {
    __syncthreads();
    llds16(Ag + k0, AsW);
    llds16(Ag + rowHop + k0, AsW + 2048);
    llds16(Bg + k0, BsW);
    llds16(Bg + rowHop + k0, BsW + 2048);
    __syncthreads();
    bf16x8 af[4], bfr[4];
#pragma unroll
    for (int mt = 0; mt < 4; mt++)
      af[mt] = *(const bf16x8*)&As[(wr * 64 + mt * 16 + (l & 15)) * 32 + (l >> 4) * 8];
#pragma unroll
    for (int nt = 0; nt < 4; nt++)
      bfr[nt] = *(const bf16x8*)&Bs[(wc * 64 + nt * 16 + (l & 15)) * 32 + (l >> 4) * 8];
#pragma unroll
    for (int mt = 0; mt < 4; mt++)
#pragma unroll
      for (int nt = 0; nt < 4; nt++)
        acc[mt][nt] = __builtin_amdgcn_mfma_f32_16x16x32_bf16(af[mt], bfr[nt], acc[mt][nt], 0, 0, 0);
  }

  const bool f32res = (EPI == EPI_RESX_BF16) ? (*flag != 0) : false;
  // C/D layout (verified m89/m91): col = lane&15, row = (lane>>4)*4 + reg
#pragma unroll
  for (int mt = 0; mt < 4; mt++) {
    const int rowb = row0 + wr * 64 + mt * 16 + ((l >> 4) << 2);
#pragma unroll
    for (int nt = 0; nt < 4; nt++) {
      const int col = col0 + wc * 64 + nt * 16 + (l & 15);
#pragma unroll
      for (int r = 0; r < 4; r++) {
        const size_t idx = (size_t)(rowb + r) * Nr + col;
        float v = acc[mt][nt][r];
        if (EPI == EPI_BF16) { outB[idx] = (bf16)v; }
        else if (EPI == EPI_BIAS_BF16) { outB[idx] = (bf16)(v + (float)bias[col]); }
        else if (EPI == EPI_BIAS_RELU_BF16) { outB[idx] = (bf16)fmaxf(v + (float)bias[col], 0.f); }
        else if (EPI == EPI_BIAS_RESB_F32) { outF[idx] = v + (float)bias[col] + (float)auxB[idx]; }
        else if (EPI == EPI_SILU_BF16) {   // in place: outB == auxB, same idx
          float s1v = (float)auxB[idx];
          float sl = s1v / (1.f + __expf(-s1v));
          outB[idx] = (bf16)(sl * v);
        }
        else if (EPI == EPI_DZ_BF16) {     // mask by relu'(z0) at same idx
          float zv = (float)auxB[idx];
          outB[idx] = (bf16)(zv > 0.f ? v : 0.f);
        }
        else if (EPI == EPI_RESX_BF16) {   // residual from raw input (dtype-aware)
          float rv = f32res ? ((const float*)resX)[idx] : (float)((const bf16*)resX)[idx];
          outB[idx] = (bf16)(v + rv);
        }
        else if (EPI == EPI_RESF_F32) {    // in place fp32: outF == resF, same idx
          outF[idx] = v + resF[idx];
        }
      }
    }
  }
}

// ---------------------------------------------------------------- GEMM (TN): C[i][j] = sum_t X[t][i]*Y[t][j] -> fp32
__global__ __launch_bounds__(256)
void k_gemm_tn(const bf16* __restrict__ X, const bf16* __restrict__ Y, int Kt,
               float* __restrict__ out)
{
  __shared__ bf16 As[128 * 36];
  __shared__ bf16 Bs[128 * 36];
  const int tid = threadIdx.x;
  const int w = tid >> 6, l = tid & 63;
  const int wr = w >> 1, wc = w & 1;
  const int row0 = blockIdx.y * 128, col0 = blockIdx.x * 128;
  const int iofs = (tid & 15) * 8;   // 0..120
  const int tp   = (tid >> 4) * 2;   // 0..30

  const f32x4 vzero = {0.f, 0.f, 0.f, 0.f};
  f32x4 acc[4][4];
#pragma unroll
  for (int i = 0; i < 4; i++)
#pragma unroll
    for (int j = 0; j < 4; j++) acc[i][j] = vzero;

  for (int t0 = 0; t0 < Kt; t0 += 32) {
    __syncthreads();
    bf16x8 a0 = *(const bf16x8*)&X[(size_t)(t0 + tp) * 1024 + row0 + iofs];
    bf16x8 a1 = *(const bf16x8*)&X[(size_t)(t0 + tp + 1) * 1024 + row0 + iofs];
    bf16x8 b0 = *(const bf16x8*)&Y[(size_t)(t0 + tp) * 1024 + col0 + iofs];
    bf16x8 b1 = *(const bf16x8*)&Y[(size_t)(t0 + tp + 1) * 1024 + col0 + iofs];
#pragma unroll
    for (int e = 0; e < 8; e++) {
      bf16x2 pa; pa[0] = a0[e]; pa[1] = a1[e];
      bf16x2 pb; pb[0] = b0[e]; pb[1] = b1[e];
      *(bf16x2*)&As[(iofs + e) * 36 + tp] = pa;
      *(bf16x2*)&Bs[(iofs + e) * 36 + tp] = pb;
    }
    __syncthreads();
    bf16x8 af[4], bfr[4];
#pragma unroll
    for (int mt = 0; mt < 4; mt++) {
      const int base = (wr * 64 + mt * 16 + (l & 15)) * 36 + (l >> 4) * 8;
      bf16x4 lo = *(const bf16x4*)&As[base];
      bf16x4 hi = *(const bf16x4*)&As[base + 4];
#pragma unroll
      for (int e = 0; e < 4; e++) { af[mt][e] = lo[e]; af[mt][4 + e] = hi[e]; }
    }
#pragma unroll
    for (int nt = 0; nt < 4; nt++) {
      const int base = (wc * 64 + nt * 16 + (l & 15)) * 36 + (l >> 4) * 8;
      bf16x4 lo = *(const bf16x4*)&Bs[base];
      bf16x4 hi = *(const bf16x4*)&Bs[base + 4];
#pragma unroll
      for (int e = 0; e < 4; e++) { bfr[nt][e] = lo[e]; bfr[nt][4 + e] = hi[e]; }
    }
#pragma unroll
    for (int mt = 0; mt < 4; mt++)
#pragma unroll
      for (int nt = 0; nt < 4; nt++)
        acc[mt][nt] = __builtin_amdgcn_mfma_f32_16x16x32_bf16(af[mt], bfr[nt], acc[mt][nt], 0, 0, 0);
  }

#pragma unroll
  for (int mt = 0; mt < 4; mt++) {
    const int rowb = row0 + wr * 64 + mt * 16 + ((l >> 4) << 2);
#pragma unroll
    for (int nt = 0; nt < 4; nt++) {
      const int col = col0 + wc * 64 + nt * 16 + (l & 15);
#pragma unroll
      for (int r = 0; r < 4; r++)
        out[(size_t)(rowb + r) * 1024 + col] = acc[mt][nt][r];
    }
  }
}

// ---------------------------------------------------------------- RMSNorm variants
__global__ __launch_bounds__(256)
void k_rmsnorm_dt(const void* __restrict__ x, const bf16* __restrict__ w, bf16* __restrict__ out,
                  const int* __restrict__ flag)
{
  const int row = blockIdx.x;
  const int tid = threadIdx.x;
  f32x4 xv;
  if (*flag) xv = *(const f32x4*)((const float*)x + (size_t)row * Dc + tid * 4);
  else       xv = cvt4(*(const bf16x4*)((const bf16*)x + (size_t)row * Dc + tid * 4));
  float ss = xv[0] * xv[0] + xv[1] * xv[1] + xv[2] * xv[2] + xv[3] * xv[3];
#pragma unroll
  for (int off = 32; off > 0; off >>= 1) ss += __shfl_down(ss, off, 64);
  __shared__ float part[4];
  if ((tid & 63) == 0) part[tid >> 6] = ss;
  __syncthreads();
  float tot = part[0] + part[1] + part[2] + part[3];
  float inv = 1.f / (sqrtf(tot) * 0.03125f + 1e-8f);
  bf16x4 wb = *(const bf16x4*)(w + tid * 4);
  bf16x4 ov;
  ov[0] = (bf16)((float)wb[0] * xv[0] * inv);
  ov[1] = (bf16)((float)wb[1] * xv[1] * inv);
  ov[2] = (bf16)((float)wb[2] * xv[2] * inv);
  ov[3] = (bf16)((float)wb[3] * xv[3] * inv);
  *(bf16x4*)(out + (size_t)row * Dc + tid * 4) = ov;
}

__global__ __launch_bounds__(256)
void k_rmsnorm_b(const bf16* __restrict__ x, const bf16* __restrict__ w, bf16* __restrict__ out)
{
  const int row = blockIdx.x;
  const int tid = threadIdx.x;
  f32x4 xv = cvt4(*(const bf16x4*)(x + (size_t)row * Dc + tid * 4));
  float ss = xv[0] * xv[0] + xv[1] * xv[1] + xv[2] * xv[2] + xv[3] * xv[3];
#pragma unroll
  for (int off = 32; off > 0; off >>= 1) ss += __shfl_down(ss, off, 64);
  __shared__ float part[4];
  if ((tid & 63) == 0) part[tid >> 6] = ss;
  __syncthreads();
  float tot = part[0] + part[1] + part[2] + part[3];
  float inv = 1.f / (sqrtf(tot) * 0.03125f + 1e-8f);
  bf16x4 wb = *(const bf16x4*)(w + tid * 4);
  bf16x4 ov;
  ov[0] = (bf16)((float)wb[0] * xv[0] * inv);
  ov[1] = (bf16)((float)wb[1] * xv[1] * inv);
  ov[2] = (bf16)((float)wb[2] * xv[2] * inv);
  ov[3] = (bf16)((float)wb[3] * xv[3] * inv);
  *(bf16x4*)(out + (size_t)row * Dc + tid * 4) = ov;
}

__global__ __launch_bounds__(256)
void k_rmsnorm_f(const float* __restrict__ x, const bf16* __restrict__ w, bf16* __restrict__ out)
{
  const int row = blockIdx.x;
  const int tid = threadIdx.x;
  f32x4 xv = *(const f32x4*)(x + (size_t)row * Dc + tid * 4);
  float ss = xv[0] * xv[0] + xv[1] * xv[1] + xv[2] * xv[2] + xv[3] * xv[3];
#pragma unroll
  for (int off = 32; off > 0; off >>= 1) ss += __shfl_down(ss, off, 64);
  __shared__ float part[4];
  if ((tid & 63) == 0) part[tid >> 6] = ss;
  __syncthreads();
  float tot = part[0] + part[1] + part[2] + part[3];
  float inv = 1.f / (sqrtf(tot) * 0.03125f + 1e-8f);
  bf16x4 wb = *(const bf16x4*)(w + tid * 4);
  bf16x4 ov;
  ov[0] = (bf16)((float)wb[0] * xv[0] * inv);
  ov[1] = (bf16)((float)wb[1] * xv[1] * inv);
  ov[2] = (bf16)((float)wb[2] * xv[2] * inv);
  ov[3] = (bf16)((float)wb[3] * xv[3] * inv);
  *(bf16x4*)(out + (size_t)row * Dc + tid * 4) = ov;
}

// ---------------------------------------------------------------- RoPE in-place on bf16 q,k
__global__ __launch_bounds__(256)
void k_rope(bf16* __restrict__ q, bf16* __restrict__ kx)
{
  const int idx = blockIdx.x * 256 + threadIdx.x;  // NT*H = 65536
  const int t = idx >> 4, hh = idx & 15;
  const int s = t & (Sc - 1);
  float sn[32], cs[32];
#pragma unroll
  for (int i = 0; i < 32; i++) {
    float f = expf(-(float)i * 0.28782313662425574f);  // ln(10000)/32
    float ang = (float)s * f;
    sn[i] = sinf(ang);
    cs[i] = cosf(ang);
  }
  for (int pass = 0; pass < 2; pass++) {
    bf16* p = (pass ? kx : q) + (size_t)t * Dc + hh * HDc;
    float xb[64], ob[64];
#pragma unroll
    for (int j = 0; j < 16; j++) *(f32x4*)&xb[j * 4] = cvt4(*(const bf16x4*)(p + j * 4));
#pragma unroll
    for (int i = 0; i < 32; i++) {
      float x1 = xb[2 * i], x2 = xb[2 * i + 1];
      ob[i] = x1 * cs[i] - x2 * sn[i];
      ob[32 + i] = x1 * sn[i] + x2 * cs[i];
    }
#pragma unroll
    for (int j = 0; j < 16; j++) {
      bf16x4 o4;
      o4[0] = (bf16)ob[j * 4]; o4[1] = (bf16)ob[j * 4 + 1];
      o4[2] = (bf16)ob[j * 4 + 2]; o4[3] = (bf16)ob[j * 4 + 3];
      *(bf16x4*)(p + j * 4) = o4;
    }
  }
}

// ---------------------------------------------------------------- causal flash attention, bf16 io / fp32 math
__global__ __launch_bounds__(64)
void k_attn(const bf16* __restrict__ q, const bf16* __restrict__ k,
            const bf16* __restrict__ v, bf16* __restrict__ o)
{
  __shared__ float Ks[16 * 64];
  __shared__ float Vs[16 * 64];
  const int blk = blockIdx.x;       // B*H*(S/64) = 1024
  const int qt = blk & 31;
  const int bh = blk >> 5;
  const int b = bh >> 4, hh = bh & 15;
  const int tid = threadIdx.x;
  const int qi = qt * 64 + tid;
  const size_t base = ((size_t)(b * Sc + qi)) * Dc + hh * HDc;

  const f32x4 vzero = {0.f, 0.f, 0.f, 0.f};
  f32x4 qr[16], oa[16];
#pragma unroll
  for (int j = 0; j < 16; j++) { qr[j] = cvt4(*(const bf16x4*)(q + base + j * 4)); oa[j] = vzero; }
  float mrun = -3.0e38f, lrun = 0.f;
  const int ntiles = (qt + 1) * 4;

  for (int t0 = 0; t0 < ntiles; t0++) {
    const int k0 = t0 * 16;
    __syncthreads();
#pragma unroll
    for (int c = 0; c < 4; c++) {
      int e = tid + c * 64;
      int rr = e >> 4, ch = (e & 15) * 4;
      size_t g = ((size_t)(b * Sc + k0 + rr)) * Dc + hh * HDc + ch;
      *(f32x4*)&Ks[rr * 64 + ch] = cvt4(*(const bf16x4*)(k + g));
      *(f32x4*)&Vs[rr * 64 + ch] = cvt4(*(const bf16x4*)(v + g));
    }
    __syncthreads();
    float s[16];
#pragma unroll
    for (int kk = 0; kk < 16; kk++) {
      f32x4 a = vzero;
#pragma unroll
      for (int j = 0; j < 16; j++) a += qr[j] * (*(const f32x4*)&Ks[kk * 64 + j * 4]);
      float sv = (a[0] + a[1] + a[2] + a[3]) * 0.125f;
      s[kk] = (k0 + kk <= qi) ? sv : -3.0e38f;
    }
    float mt = s[0];
#pragma unroll
    for (int kk = 1; kk < 16; kk++) mt = fmaxf(mt, s[kk]);
    float mnew = fmaxf(mrun, mt);
    float alpha = __expf(mrun - mnew);
    float p[16];
    float ps = 0.f;
#pragma unroll
    for (int kk = 0; kk < 16; kk++) { p[kk] = __expf(s[kk] - mnew); ps += p[kk]; }
    lrun = lrun * alpha + ps;
#pragma unroll
    for (int j = 0; j < 16; j++) oa[j] = oa[j] * alpha;
#pragma unroll
    for (int kk = 0; kk < 16; kk++) {
      float pk = p[kk];
#pragma unroll
      for (int j = 0; j < 16; j++) oa[j] += pk * (*(const f32x4*)&Vs[kk * 64 + j * 4]);
    }
    mrun = mnew;
  }
  float inv = 1.f / lrun;
#pragma unroll
  for (int j = 0; j < 16; j++) {
    f32x4 ov = oa[j] * inv;
    bf16x4 os;
    os[0] = (bf16)ov[0]; os[1] = (bf16)ov[1]; os[2] = (bf16)ov[2]; os[3] = (bf16)ov[3];
    *(bf16x4*)(o + base + j * 4) = os;
  }
}

// ---------------------------------------------------------------- elementwise relu (x8)
__global__ __launch_bounds__(256)
void k_relu(const bf16* __restrict__ src, bf16* __restrict__ dst)
{
  int i = blockIdx.x * 256 + threadIdx.x;  // n/8 threads
  bf16x8 v = ((const bf16x8*)src)[i];
  bf16x8 o;
#pragma unroll
  for (int e = 0; e < 8; e++) o[e] = ((float)v[e] > 0.f) ? v[e] : (bf16)0.f;
  ((bf16x8*)dst)[i] = o;
}

// ---------------------------------------------------------------- dp = 2(pred-vf)/M in-place over pred + loss
__global__ __launch_bounds__(256)
void k_dpred(bf16* __restrict__ predDp, const bf16* __restrict__ vf, float* __restrict__ loss)
{
  const size_t idx = (size_t)blockIdx.x * 256 + threadIdx.x;  // NT*M threads
  float e = (float)predDp[idx] - (float)vf[idx];
  predDp[idx] = (bf16)(e * (2.0f / 1024.0f));
  float lacc = e * e;
#pragma unroll
  for (int off = 32; off > 0; off >>= 1) lacc += __shfl_down(lacc, off, 64);
  if ((threadIdx.x & 63) == 0) atomicAdd(loss, lacc);
}

// ---------------------------------------------------------------- colsum: out[c] = sum_r X[r][c]
__global__ __launch_bounds__(256)
void k_colsum(const bf16* __restrict__ X, float* __restrict__ out, int R, int C)
{
  int c = blockIdx.x * 256 + threadIdx.x;
  float s = 0.f;
#pragma unroll 8
  for (int r = 0; r < R; r++) s += (float)X[(size_t)r * C + c];
  out[c] = s;
}

// ---------------------------------------------------------------- dtype-aware param/momentum update -> fp32 d_out
// g0wF/g1wF live inside outM (fp32); thread i reads/writes outM[i] bijectively.
__global__ __launch_bounds__(256)
void k_update_dt(const void* __restrict__ p0w, const void* __restrict__ p0b,
                 const void* __restrict__ p1w, const void* __restrict__ p1b,
                 const void* __restrict__ m0w, const void* __restrict__ m0b,
                 const void* __restrict__ m1w, const void* __restrict__ m1b,
                 const float* __restrict__ g0wF, const float* __restrict__ g0b,
                 const float* __restrict__ g1wF, const float* __restrict__ g1b,
                 const float* __restrict__ loss, const int* __restrict__ flag,
                 float* __restrict__ outP, float* __restrict__ outM)
{
  const int i = blockIdx.x * 256 + threadIdx.x;  // < 2099200 exactly
  const bool upd = (loss[0] >= 0.1f * 1024.f * 4096.f);  // avg_loss >= THRESH
  const bool f32 = (*flag != 0);
  constexpr int W = 1024 * 1024;
  const void *pp, *pm; int j; float g;
  if (i < W) { pp = p0w; pm = m0w; j = i; g = g0wF[i]; }
  else if (i < W + 1024) { j = i - W; pp = p0b; pm = m0b; g = g0b[j]; }
  else if (i < 2 * W + 1024) { j = i - W - 1024; pp = p1w; pm = m1w; g = g1wF[j]; }
  else { j = i - 2 * W - 1024; pp = p1b; pm = m1b; g = g1b[j]; }
  float p = f32 ? ((const float*)pp)[j] : (float)((const bf16*)pp)[j];
  float m = f32 ? ((const float*)pm)[j] : (float)((const bf16*)pm)[j];
  float nm = 0.9f * m - 0.01f * g;
  float np = 0.99f * p + nm;
  outP[i] = upd ? np : p;
  outM[i] = upd ? nm : m;
}

// ================================================================ host
// Outputs are FP32 (reference dtype). Workspace ~56 MiB.
extern "C" void kernel_launch(void* const* d_in, const int* in_sizes, int n_in,
                              void* d_out, int out_size, void* d_ws, size_t ws_size,
                              hipStream_t stream)
{
  (void)in_sizes; (void)n_in; (void)out_size; (void)ws_size;
  const void* x   = d_in[0];
  const void* wq  = d_in[2];
  const void* wk  = d_in[3];
  const void* wv  = d_in[4];
  const void* wo  = d_in[5];
  const void* n1  = d_in[6];
  const void* n2  = d_in[7];
  const void* n3  = d_in[8];
  const void* fw1 = d_in[9];
  const void* fw2 = d_in[10];
  const void* fw3 = d_in[11];
  const void* pkw = d_in[12];
  const void* pkb = d_in[13];
  const void* pvw = d_in[14];
  const void* pvb = d_in[15];
  const void* pqw = d_in[16];
  const void* pqb = d_in[17];
  const void* l0w = d_in[18];
  const void* l0b = d_in[19];
  const void* l1w = d_in[20];
  const void* l1b = d_in[21];
  const void* m0w = d_in[22];
  const void* m0b = d_in[23];
  const void* m1w = d_in[24];
  const void* m1b = d_in[25];

  char* ws = (char*)d_ws;
  size_t off = 0;
  auto alloc = [&](size_t bytes) -> char* {
    char* p = ws + off;
    off += (bytes + 255) & ~(size_t)255;
    return p;
  };

  const size_t DD = (size_t)Dc * Dc;   // 1M elems
  const size_t ND = (size_t)NTc * Dc;  // 4M elems
  const size_t MB8 = 2 * ND;           // 8 MiB
  const size_t M1 = DD;                // 1M elems

  // --- weight region W: 8M bf16 elems (16 MiB), phase-cycled
  bf16* W = (bf16*)alloc(2 * 8 * M1);
  bf16 *wqT = W, *wkT = W + M1, *wvT = W + 2 * M1, *woT = W + 3 * M1;
  bf16 *pqT = W + 4 * M1, *pkT = W + 5 * M1, *pvT = W + 6 * M1, *l0T = W + 7 * M1;
  bf16 *l1T = W + M1;          // staged after wo-GEMM (wkT dead)
  bf16 *l1c = W;               // staged after pred-GEMM (over wqT)
  bf16 *w1T = W + 4 * M1;      // staged after z0-GEMM (pqT..l0T dead)
  bf16 *w2T = W;               // staged after grads (l1c/l1T dead)
  bf16 *w3T = W + 4 * M1;      // staged after ffn1 (w1T dead)

  // --- 5 activation slots, B0..B3 contiguous (s1 spans them at FFN)
  bf16* B0 = (bf16*)alloc(MB8);  // q -> hn2 -> h1r -> h1 -> (s1)
  bf16* B1 = (bf16*)alloc(MB8);  // k -> qlmm -> pred/dp -> (s1)
  bf16* B2 = (bf16*)alloc(MB8);  // v -> kf -> (s1)
  bf16* B3 = (bf16*)alloc(MB8);  // o -> vf -> dz -> (s1)
  bf16* B4 = (bf16*)alloc(MB8);  // hb -> z0 -> hn3
  bf16* s1 = B0;                 // [NT][F] = 32 MiB

  // --- smalls
  float* g0b = (float*)alloc(4 * 1024);
  float* g1b = (float*)alloc(4 * 1024);
  float* lossb = (float*)alloc(256);
  int*   flag  = (int*)alloc(256);
  bf16* n1c = (bf16*)alloc(2 * 1024);
  bf16* n2c = (bf16*)alloc(2 * 1024);
  bf16* n3c = (bf16*)alloc(2 * 1024);
  bf16* bqc = (bf16*)alloc(2 * 1024);
  bf16* bkc = (bf16*)alloc(2 * 1024);
  bf16* bvc = (bf16*)alloc(2 * 1024);
  bf16* b0c = (bf16*)alloc(2 * 1024);
  bf16* b1c = (bf16*)alloc(2 * 1024);

  // --- output regions (fp32)
  float* outX = (float*)d_out;                 // hn(bf16 head), then h2 fp32, then final out fp32
  float* outP = outX + ND;                     // new params (l0w,l0b,l1w,l1b)
  float* outM = outP + (2 * DD + 2048);        // new momenta; hosts g0wF/g1wF pre-update
  float* g0wF = outM;                          // [1M] grad l0_w
  float* g1wF = outM + M1 + 1024;              // [1M] grad l1_w
  bf16*  hn   = (bf16*)outX;                   // bf16 hn in first 8 MiB of outX, dead before h2

  const dim3 tb(32, 8);

  hipMemsetAsync(lossb, 0, sizeof(float), stream);
  k_detect<<<1, 64, 0, stream>>>((const unsigned short*)x, flag);

  // small cvts
  k_cvt<<<1, 256, 0, stream>>>(n1, n1c, 256, flag);
  k_cvt<<<1, 256, 0, stream>>>(n2, n2c, 256, flag);
  k_cvt<<<1, 256, 0, stream>>>(n3, n3c, 256, flag);
  k_cvt<<<1, 256, 0, stream>>>(pqb, bqc, 256, flag);
  k_cvt<<<1, 256, 0, stream>>>(pkb, bkc, 256, flag);
  k_cvt<<<1, 256, 0, stream>>>(pvb, bvc, 256, flag);
  k_cvt<<<1, 256, 0, stream>>>(l0b, b0c, 256, flag);
  k_cvt<<<1, 256, 0, stream>>>(l1b, b1c, 256, flag);

  // phase-1 weight transposes
  k_transpose_dt<<<dim3(32, 32), tb, 0, stream>>>(wq, wqT, Dc, Dc, flag);
  k_transpose_dt<<<dim3(32, 32), tb, 0, stream>>>(wk, wkT, Dc, Dc, flag);
  k_transpose_dt<<<dim3(32, 32), tb, 0, stream>>>(wv, wvT, Dc, Dc, flag);
  k_transpose_dt<<<dim3(32, 32), tb, 0, stream>>>(wo, woT, Dc, Dc, flag);
  k_transpose_dt<<<dim3(32, 32), tb, 0, stream>>>(pqw, pqT, Dc, Mc, flag);
  k_transpose_dt<<<dim3(32, 32), tb, 0, stream>>>(pkw, pkT, Dc, Mc, flag);
  k_transpose_dt<<<dim3(32, 32), tb, 0, stream>>>(pvw, pvT, Dc, Mc, flag);
  k_transpose_dt<<<dim3(32, 32), tb, 0, stream>>>(l0w, l0T, Mc, Mc, flag);

  // ---- attention
  k_rmsnorm_dt<<<NTc, 256, 0, stream>>>(x, n1c, hn, flag);
  k_gemm<EPI_BF16><<<dim3(8, 32), 256, 0, stream>>>(hn, wqT, NTc, Dc, Dc, nullptr, B0, nullptr, nullptr, nullptr, nullptr, nullptr);
  k_gemm<EPI_BF16><<<dim3(8, 32), 256, 0, stream>>>(hn, wkT, NTc, Dc, Dc, nullptr, B1, nullptr, nullptr, nullptr, nullptr, nullptr);
  k_gemm<EPI_BF16><<<dim3(8, 32), 256, 0, stream>>>(hn, wvT, NTc, Dc, Dc, nullptr, B2, nullptr, nullptr, nullptr, nullptr, nullptr);
  k_rope<<<256, 256, 0, stream>>>(B0, B1);
  k_attn<<<1024, 64, 0, stream>>>(B0, B1, B2, B3);
  k_gemm<EPI_RESX_BF16><<<dim3(8, 32), 256, 0, stream>>>(B3, woT, NTc, Dc, Dc, nullptr, B4, nullptr, nullptr, nullptr, x, flag);  // hb -> B4
  k_transpose_dt<<<dim3(32, 32), tb, 0, stream>>>(l1w, l1T, Mc, Mc, flag);

  // ---- LMM forward
  k_rmsnorm_b<<<NTc, 256, 0, stream>>>(B4, n2c, B0);   // hn2 -> B0
  k_gemm<EPI_BIAS_BF16><<<dim3(8, 32), 256, 0, stream>>>(B0, pqT, NTc, Mc, Dc, nullptr, B1, bqc, nullptr, nullptr, nullptr, nullptr);  // qlmm
  k_gemm<EPI_BIAS_BF16><<<dim3(8, 32), 256, 0, stream>>>(B0, pkT, NTc, Mc, Dc, nullptr, B2, bkc, nullptr, nullptr, nullptr, nullptr);  // kf
  k_gemm<EPI_BIAS_BF16><<<dim3(8, 32), 256, 0, stream>>>(B0, pvT, NTc, Mc, Dc, nullptr, B3, bvc, nullptr, nullptr, nullptr, nullptr);  // vf
  k_gemm<EPI_BIAS_RELU_BF16><<<dim3(8, 32), 256, 0, stream>>>(B1, l0T, NTc, Mc, Mc, nullptr, B0, b0c, nullptr, nullptr, nullptr, nullptr);  // h1r
  // h2 = h1r@l1T + l1b + hb -> fp32 in outX (overwrites bf16 hn region; hn is dead)
  k_gemm<EPI_BIAS_RESB_F32><<<dim3(8, 32), 256, 0, stream>>>(B0, l1T, NTc, Mc, Mc, outX, nullptr, b1c, B4, nullptr, nullptr, nullptr);

  // ---- LMM loss fwd/bwd
  k_gemm<EPI_BIAS_BF16><<<dim3(8, 32), 256, 0, stream>>>(B2, l0T, NTc, Mc, Mc, nullptr, B4, b0c, nullptr, nullptr, nullptr, nullptr);  // z0 -> B4
  k_transpose_dt<<<dim3(128, 32), tb, 0, stream>>>(fw1, w1T, Dc, Fc, flag);     // stage w1T (pqT..l0T dead)
  k_relu<<<2048, 256, 0, stream>>>(B4, B0);            // h1 -> B0
  k_gemm<EPI_BIAS_BF16><<<dim3(8, 32), 256, 0, stream>>>(B0, l1T, NTc, Mc, Mc, nullptr, B1, b1c, nullptr, nullptr, nullptr, nullptr);  // pred -> B1
  k_cvt<<<1024, 256, 0, stream>>>(l1w, l1c, (int)(DD / 4), flag);
  k_dpred<<<16384, 256, 0, stream>>>(B1, B3, lossb);   // dp in-place over pred
  k_gemm<EPI_DZ_BF16><<<dim3(8, 32), 256, 0, stream>>>(B1, l1c, NTc, Mc, Mc, nullptr, B3, nullptr, B4, nullptr, nullptr, nullptr);     // dz -> B3
  k_gemm_tn<<<dim3(8, 8), 256, 0, stream>>>(B0, B1, NTc, g1wF);   // g1w = h1^T dp (fp32)
  k_gemm_tn<<<dim3(8, 8), 256, 0, stream>>>(B2, B3, NTc, g0wF);   // g0w = kf^T dz (fp32)
  k_colsum<<<4, 256, 0, stream>>>(B1, g1b, NTc, Mc);
  k_colsum<<<4, 256, 0, stream>>>(B3, g0b, NTc, Mc);
  k_update_dt<<<8200, 256, 0, stream>>>(l0w, l0b, l1w, l1b, m0w, m0b, m1w, m1b,
                                        g0wF, g0b, g1wF, g1b, lossb, flag, outP, outM);

  // ---- FFN (all B-slots free; h2 fp32 in outX)
  k_transpose_dt<<<dim3(128, 32), tb, 0, stream>>>(fw2, w2T, Dc, Fc, flag);     // stage w2T (l1c/l1T dead)
  k_rmsnorm_f<<<NTc, 256, 0, stream>>>(outX, n3c, B4); // hn3 -> B4
  k_gemm<EPI_BF16><<<dim3(32, 32), 256, 0, stream>>>(B4, w1T, NTc, Fc, Dc, nullptr, s1, nullptr, nullptr, nullptr, nullptr, nullptr);
  k_transpose_dt<<<dim3(32, 128), tb, 0, stream>>>(fw3, w3T, Fc, Dc, flag);     // stage w3T (w1T dead)
  k_gemm<EPI_SILU_BF16><<<dim3(32, 32), 256, 0, stream>>>(B4, w2T, NTc, Fc, Dc, nullptr, s1, nullptr, s1, nullptr, nullptr, nullptr);
  // out = s1@w3T + h2  (fp32 in-place over outX)
  k_gemm<EPI_RESF_F32><<<dim3(8, 32), 256, 0, stream>>>(s1, w3T, NTc, Dc, Fc, outX, nullptr, nullptr, nullptr, outX, nullptr, nullptr);
}

// Round 7
// 2189.267 us; speedup vs baseline: 2.0798x; 2.0798x over previous
//
#include <hip/hip_runtime.h>
#include <cstdint>
#include <cstddef>

typedef __bf16 bf16;
typedef __bf16 bf16x2 __attribute__((ext_vector_type(2)));
typedef __bf16 bf16x4 __attribute__((ext_vector_type(4)));
typedef __bf16 bf16x8 __attribute__((ext_vector_type(8)));
typedef float  f32x4  __attribute__((ext_vector_type(4)));
typedef __attribute__((address_space(1))) unsigned int u32_g;
typedef __attribute__((address_space(3))) unsigned int u32_l;

#define DI __device__ __forceinline__

constexpr int Bc = 2, Sc = 2048, Dc = 1024, Hc = 16, HDc = 64, Fc = 4096, Mc = 1024;
constexpr int NTc = Bc * Sc;  // 4096 tokens

DI void llds16(const bf16* g, bf16* l) {
  __builtin_amdgcn_global_load_lds((const u32_g*)g, (u32_l*)l, 16, 0, 0);
}
DI f32x4 cvt4(bf16x4 a) {
  f32x4 r; r[0] = (float)a[0]; r[1] = (float)a[1]; r[2] = (float)a[2]; r[3] = (float)a[3];
  return r;
}

// ---------------------------------------------------------------- dtype detector (inputs)
__global__ void k_detect(const unsigned short* __restrict__ x, int* __restrict__ flag)
{
  const int tid = threadIdx.x;  // 64
  int cnt = 0;
#pragma unroll
  for (int i = 0; i < 8; i++) {
    unsigned short h = x[tid * 8 + i];
    int e = (h >> 7) & 0xFF;
    if (e < 96 || e > 160) cnt++;
  }
#pragma unroll
  for (int off = 32; off > 0; off >>= 1) cnt += __shfl_down(cnt, off, 64);
  if (tid == 0) *flag = (cnt > 32) ? 1 : 0;
}

// ---------------------------------------------------------------- dtype-aware convert to bf16
__global__ __launch_bounds__(256)
void k_cvt(const void* __restrict__ src, bf16* __restrict__ dst, int n4, const int* __restrict__ flag)
{
  int i = blockIdx.x * 256 + threadIdx.x;
  if (i >= n4) return;
  bf16x4 o;
  if (*flag) {
    f32x4 v = ((const f32x4*)src)[i];
    o[0] = (bf16)v[0]; o[1] = (bf16)v[1]; o[2] = (bf16)v[2]; o[3] = (bf16)v[3];
  } else {
    o = ((const bf16x4*)src)[i];
  }
  ((bf16x4*)dst)[i] = o;
}

// ---------------------------------------------------------------- dtype-aware transpose [R][C] -> bf16 [C][R]
__global__ void k_transpose_dt(const void* __restrict__ src, bf16* __restrict__ dst,
                               int R, int C, const int* __restrict__ flag)
{
  __shared__ bf16 tile[32][33];
  const int c0 = blockIdx.x * 32, r0 = blockIdx.y * 32;
  const int tx = threadIdx.x, ty = threadIdx.y;
  const bool f32 = (*flag != 0);
  for (int i = ty; i < 32; i += 8) {
    size_t idx = (size_t)(r0 + i) * C + (c0 + tx);
    tile[i][tx] = f32 ? (bf16)((const float*)src)[idx] : ((const bf16*)src)[idx];
  }
  __syncthreads();
  for (int i = ty; i < 32; i += 8)
    dst[(size_t)(c0 + i) * R + (r0 + tx)] = tile[tx][i];
}

// ---------------------------------------------------------------- GEMM (NT): C[M][N] = A[M][K] * Bt[N][K]^T
enum EpiMode { EPI_BF16 = 0, EPI_BIAS_BF16, EPI_BIAS_RELU_BF16, EPI_BIAS_RESB_F32,
               EPI_SILU_BF16, EPI_DZ_BF16, EPI_RESX_BF16, EPI_RESF_F32 };

template <int EPI>
__global__ __launch_bounds__(256)
void k_gemm(const bf16* __restrict__ A, const bf16* __restrict__ Bt,
            int Mr, int Nr, int Kr,
            float* outF, bf16* outB,
            const bf16* __restrict__ bias, const bf16* auxB,
            const float* resF,
            const void* __restrict__ resX, const int* __restrict__ flag)
{
  __shared__ bf16 As[128 * 32];
  __shared__ bf16 Bs[128 * 32];
  const int tid = threadIdx.x;
  const int w = tid >> 6, l = tid & 63;
  const int wr = w >> 1, wc = w & 1;
  const int row0 = blockIdx.y * 128, col0 = blockIdx.x * 128;

  const f32x4 vzero = {0.f, 0.f, 0.f, 0.f};
  f32x4 acc[4][4];
#pragma unroll
  for (int i = 0; i < 4; i++)
#pragma unroll
    for (int j = 0; j < 4; j++) acc[i][j] = vzero;

  const bf16* Ag = A + (size_t)(row0 + w * 16 + (l >> 2)) * Kr + ((l & 3) << 3);
  const bf16* Bg = Bt + (size_t)(col0 + w * 16 + (l >> 2)) * Kr + ((l & 3) << 3);
  bf16* AsW = &As[w * 512];
  bf16* BsW = &Bs[w * 512];
  const size_t rowHop = (size_t)64 * Kr;

  for (int k0 = 0; k0 < Kr; k0 += 32) {
    __syncthreads();
    llds16(Ag + k0, AsW);
    llds16(Ag + rowHop + k0, AsW + 2048);
    llds16(Bg + k0, BsW);
    llds16(Bg + rowHop + k0, BsW + 2048);
    __syncthreads();
    bf16x8 af[4], bfr[4];
#pragma unroll
    for (int mt = 0; mt < 4; mt++)
      af[mt] = *(const bf16x8*)&As[(wr * 64 + mt * 16 + (l & 15)) * 32 + (l >> 4) * 8];
#pragma unroll
    for (int nt = 0; nt < 4; nt++)
      bfr[nt] = *(const bf16x8*)&Bs[(wc * 64 + nt * 16 + (l & 15)) * 32 + (l >> 4) * 8];
#pragma unroll
    for (int mt = 0; mt < 4; mt++)
#pragma unroll
      for (int nt = 0; nt < 4; nt++)
        acc[mt][nt] = __builtin_amdgcn_mfma_f32_16x16x32_bf16(af[mt], bfr[nt], acc[mt][nt], 0, 0, 0);
  }

  const bool f32res = (EPI == EPI_RESX_BF16) ? (*flag != 0) : false;
  // C/D layout (verified m89/m91): col = lane&15, row = (lane>>4)*4 + reg
#pragma unroll
  for (int mt = 0; mt < 4; mt++) {
    const int rowb = row0 + wr * 64 + mt * 16 + ((l >> 4) << 2);
#pragma unroll
    for (int nt = 0; nt < 4; nt++) {
      const int col = col0 + wc * 64 + nt * 16 + (l & 15);
#pragma unroll
      for (int r = 0; r < 4; r++) {
        const size_t idx = (size_t)(rowb + r) * Nr + col;
        float v = acc[mt][nt][r];
        if (EPI == EPI_BF16) { outB[idx] = (bf16)v; }
        else if (EPI == EPI_BIAS_BF16) { outB[idx] = (bf16)(v + (float)bias[col]); }
        else if (EPI == EPI_BIAS_RELU_BF16) { outB[idx] = (bf16)fmaxf(v + (float)bias[col], 0.f); }
        else if (EPI == EPI_BIAS_RESB_F32) { outF[idx] = v + (float)bias[col] + (float)auxB[idx]; }
        else if (EPI == EPI_SILU_BF16) {   // in place: outB == auxB, same idx
          float s1v = (float)auxB[idx];
          float sl = s1v / (1.f + __expf(-s1v));
          outB[idx] = (bf16)(sl * v);
        }
        else if (EPI == EPI_DZ_BF16) {     // mask by relu'(z0) at same idx
          float zv = (float)auxB[idx];
          outB[idx] = (bf16)(zv > 0.f ? v : 0.f);
        }
        else if (EPI == EPI_RESX_BF16) {   // residual from raw input (dtype-aware)
          float rv = f32res ? ((const float*)resX)[idx] : (float)((const bf16*)resX)[idx];
          outB[idx] = (bf16)(v + rv);
        }
        else if (EPI == EPI_RESF_F32) {    // in place fp32: outF == resF, same idx
          outF[idx] = v + resF[idx];
        }
      }
    }
  }
}

// ---------------------------------------------------------------- GEMM (TN): C[i][j] = sum_t X[t][i]*Y[t][j] -> fp32
__global__ __launch_bounds__(256)
void k_gemm_tn(const bf16* __restrict__ X, const bf16* __restrict__ Y, int Kt,
               float* __restrict__ out)
{
  __shared__ bf16 As[128 * 36];
  __shared__ bf16 Bs[128 * 36];
  const int tid = threadIdx.x;
  const int w = tid >> 6, l = tid & 63;
  const int wr = w >> 1, wc = w & 1;
  const int row0 = blockIdx.y * 128, col0 = blockIdx.x * 128;
  const int iofs = (tid & 15) * 8;   // 0..120
  const int tp   = (tid >> 4) * 2;   // 0..30

  const f32x4 vzero = {0.f, 0.f, 0.f, 0.f};
  f32x4 acc[4][4];
#pragma unroll
  for (int i = 0; i < 4; i++)
#pragma unroll
    for (int j = 0; j < 4; j++) acc[i][j] = vzero;

  for (int t0 = 0; t0 < Kt; t0 += 32) {
    __syncthreads();
    bf16x8 a0 = *(const bf16x8*)&X[(size_t)(t0 + tp) * 1024 + row0 + iofs];
    bf16x8 a1 = *(const bf16x8*)&X[(size_t)(t0 + tp + 1) * 1024 + row0 + iofs];
    bf16x8 b0 = *(const bf16x8*)&Y[(size_t)(t0 + tp) * 1024 + col0 + iofs];
    bf16x8 b1 = *(const bf16x8*)&Y[(size_t)(t0 + tp + 1) * 1024 + col0 + iofs];
#pragma unroll
    for (int e = 0; e < 8; e++) {
      bf16x2 pa; pa[0] = a0[e]; pa[1] = a1[e];
      bf16x2 pb; pb[0] = b0[e]; pb[1] = b1[e];
      *(bf16x2*)&As[(iofs + e) * 36 + tp] = pa;
      *(bf16x2*)&Bs[(iofs + e) * 36 + tp] = pb;
    }
    __syncthreads();
    bf16x8 af[4], bfr[4];
#pragma unroll
    for (int mt = 0; mt < 4; mt++) {
      const int base = (wr * 64 + mt * 16 + (l & 15)) * 36 + (l >> 4) * 8;
      bf16x4 lo = *(const bf16x4*)&As[base];
      bf16x4 hi = *(const bf16x4*)&As[base + 4];
#pragma unroll
      for (int e = 0; e < 4; e++) { af[mt][e] = lo[e]; af[mt][4 + e] = hi[e]; }
    }
#pragma unroll
    for (int nt = 0; nt < 4; nt++) {
      const int base = (wc * 64 + nt * 16 + (l & 15)) * 36 + (l >> 4) * 8;
      bf16x4 lo = *(const bf16x4*)&Bs[base];
      bf16x4 hi = *(const bf16x4*)&Bs[base + 4];
#pragma unroll
      for (int e = 0; e < 4; e++) { bfr[nt][e] = lo[e]; bfr[nt][4 + e] = hi[e]; }
    }
#pragma unroll
    for (int mt = 0; mt < 4; mt++)
#pragma unroll
      for (int nt = 0; nt < 4; nt++)
        acc[mt][nt] = __builtin_amdgcn_mfma_f32_16x16x32_bf16(af[mt], bfr[nt], acc[mt][nt], 0, 0, 0);
  }

#pragma unroll
  for (int mt = 0; mt < 4; mt++) {
    const int rowb = row0 + wr * 64 + mt * 16 + ((l >> 4) << 2);
#pragma unroll
    for (int nt = 0; nt < 4; nt++) {
      const int col = col0 + wc * 64 + nt * 16 + (l & 15);
#pragma unroll
      for (int r = 0; r < 4; r++)
        out[(size_t)(rowb + r) * 1024 + col] = acc[mt][nt][r];
    }
  }
}

// ---------------------------------------------------------------- RMSNorm variants
__global__ __launch_bounds__(256)
void k_rmsnorm_dt(const void* __restrict__ x, const bf16* __restrict__ w, bf16* __restrict__ out,
                  const int* __restrict__ flag)
{
  const int row = blockIdx.x;
  const int tid = threadIdx.x;
  f32x4 xv;
  if (*flag) xv = *(const f32x4*)((const float*)x + (size_t)row * Dc + tid * 4);
  else       xv = cvt4(*(const bf16x4*)((const bf16*)x + (size_t)row * Dc + tid * 4));
  float ss = xv[0] * xv[0] + xv[1] * xv[1] + xv[2] * xv[2] + xv[3] * xv[3];
#pragma unroll
  for (int off = 32; off > 0; off >>= 1) ss += __shfl_down(ss, off, 64);
  __shared__ float part[4];
  if ((tid & 63) == 0) part[tid >> 6] = ss;
  __syncthreads();
  float tot = part[0] + part[1] + part[2] + part[3];
  float inv = 1.f / (sqrtf(tot) * 0.03125f + 1e-8f);
  bf16x4 wb = *(const bf16x4*)(w + tid * 4);
  bf16x4 ov;
  ov[0] = (bf16)((float)wb[0] * xv[0] * inv);
  ov[1] = (bf16)((float)wb[1] * xv[1] * inv);
  ov[2] = (bf16)((float)wb[2] * xv[2] * inv);
  ov[3] = (bf16)((float)wb[3] * xv[3] * inv);
  *(bf16x4*)(out + (size_t)row * Dc + tid * 4) = ov;
}

__global__ __launch_bounds__(256)
void k_rmsnorm_b(const bf16* __restrict__ x, const bf16* __restrict__ w, bf16* __restrict__ out)
{
  const int row = blockIdx.x;
  const int tid = threadIdx.x;
  f32x4 xv = cvt4(*(const bf16x4*)(x + (size_t)row * Dc + tid * 4));
  float ss = xv[0] * xv[0] + xv[1] * xv[1] + xv[2] * xv[2] + xv[3] * xv[3];
#pragma unroll
  for (int off = 32; off > 0; off >>= 1) ss += __shfl_down(ss, off, 64);
  __shared__ float part[4];
  if ((tid & 63) == 0) part[tid >> 6] = ss;
  __syncthreads();
  float tot = part[0] + part[1] + part[2] + part[3];
  float inv = 1.f / (sqrtf(tot) * 0.03125f + 1e-8f);
  bf16x4 wb = *(const bf16x4*)(w + tid * 4);
  bf16x4 ov;
  ov[0] = (bf16)((float)wb[0] * xv[0] * inv);
  ov[1] = (bf16)((float)wb[1] * xv[1] * inv);
  ov[2] = (bf16)((float)wb[2] * xv[2] * inv);
  ov[3] = (bf16)((float)wb[3] * xv[3] * inv);
  *(bf16x4*)(out + (size_t)row * Dc + tid * 4) = ov;
}

__global__ __launch_bounds__(256)
void k_rmsnorm_f(const float* __restrict__ x, const bf16* __restrict__ w, bf16* __restrict__ out)
{
  const int row = blockIdx.x;
  const int tid = threadIdx.x;
  f32x4 xv = *(const f32x4*)(x + (size_t)row * Dc + tid * 4);
  float ss = xv[0] * xv[0] + xv[1] * xv[1] + xv[2] * xv[2] + xv[3] * xv[3];
#pragma unroll
  for (int off = 32; off > 0; off >>= 1) ss += __shfl_down(ss, off, 64);
  __shared__ float part[4];
  if ((tid & 63) == 0) part[tid >> 6] = ss;
  __syncthreads();
  float tot = part[0] + part[1] + part[2] + part[3];
  float inv = 1.f / (sqrtf(tot) * 0.03125f + 1e-8f);
  bf16x4 wb = *(const bf16x4*)(w + tid * 4);
  bf16x4 ov;
  ov[0] = (bf16)((float)wb[0] * xv[0] * inv);
  ov[1] = (bf16)((float)wb[1] * xv[1] * inv);
  ov[2] = (bf16)((float)wb[2] * xv[2] * inv);
  ov[3] = (bf16)((float)wb[3] * xv[3] * inv);
  *(bf16x4*)(out + (size_t)row * Dc + tid * 4) = ov;
}

// ---------------------------------------------------------------- RoPE in-place on bf16 q,k
__global__ __launch_bounds__(256)
void k_rope(bf16* __restrict__ q, bf16* __restrict__ kx)
{
  const int idx = blockIdx.x * 256 + threadIdx.x;  // NT*H = 65536
  const int t = idx >> 4, hh = idx & 15;
  const int s = t & (Sc - 1);
  float sn[32], cs[32];
#pragma unroll
  for (int i = 0; i < 32; i++) {
    float f = expf(-(float)i * 0.28782313662425574f);  // ln(10000)/32
    float ang = (float)s * f;
    sn[i] = sinf(ang);
    cs[i] = cosf(ang);
  }
  for (int pass = 0; pass < 2; pass++) {
    bf16* p = (pass ? kx : q) + (size_t)t * Dc + hh * HDc;
    float xb[64], ob[64];
#pragma unroll
    for (int j = 0; j < 16; j++) *(f32x4*)&xb[j * 4] = cvt4(*(const bf16x4*)(p + j * 4));
#pragma unroll
    for (int i = 0; i < 32; i++) {
      float x1 = xb[2 * i], x2 = xb[2 * i + 1];
      ob[i] = x1 * cs[i] - x2 * sn[i];
      ob[32 + i] = x1 * sn[i] + x2 * cs[i];
    }
#pragma unroll
    for (int j = 0; j < 16; j++) {
      bf16x4 o4;
      o4[0] = (bf16)ob[j * 4]; o4[1] = (bf16)ob[j * 4 + 1];
      o4[2] = (bf16)ob[j * 4 + 2]; o4[3] = (bf16)ob[j * 4 + 3];
      *(bf16x4*)(p + j * 4) = o4;
    }
  }
}

// ---------------------------------------------------------------- MFMA flash attention
// grid: B*H*(S/64) = 1024 blocks, 256 threads (4 waves). Wave w owns q rows
// [qt*64 + w*16, +16). QK^T and PV are NT-MFMAs with the same verified fragment
// mapping as k_gemm. P round-trips LDS (C-layout -> A-layout, m120 pattern).
// Rows padded to 72 elems: b128 reads are <=2-way bank-aliased (free, m136).
__global__ __launch_bounds__(256)
void k_attn(const bf16* __restrict__ q, const bf16* __restrict__ kx,
            const bf16* __restrict__ v, bf16* __restrict__ o)
{
  constexpr int PAD = 72;
  __shared__ bf16 Ks[64 * PAD];
  __shared__ bf16 Vt[64 * PAD];        // Vt[d][kk]
  __shared__ bf16 Ps[4][16 * PAD];     // per-wave P buffer

  const int blk = blockIdx.x;
  const int qt = blk & 31;
  const int bh = blk >> 5;
  const int b = bh >> 4, hh = bh & 15;
  const int tid = threadIdx.x;
  const int w = tid >> 6, l = tid & 63;
  const int quad = l >> 4, c = l & 15;

  // Q A-frags (m = c, k = quad*8+j), pre-scaled by 1/sqrt(HD)=0.125 (exact in bf16)
  const int qrow = qt * 64 + w * 16 + c;
  const size_t qbase = ((size_t)(b * Sc + qrow)) * Dc + hh * HDc;
  bf16x8 qf0 = *(const bf16x8*)(q + qbase + quad * 8);
  bf16x8 qf1 = *(const bf16x8*)(q + qbase + 32 + quad * 8);
#pragma unroll
  for (int j = 0; j < 8; j++) {
    qf0[j] = (bf16)((float)qf0[j] * 0.125f);
    qf1[j] = (bf16)((float)qf1[j] * 0.125f);
  }

  const f32x4 vzero = {0.f, 0.f, 0.f, 0.f};
  f32x4 oacc[4];
#pragma unroll
  for (int nt = 0; nt < 4; nt++) oacc[nt] = vzero;
  float mrun[4] = {-3.0e38f, -3.0e38f, -3.0e38f, -3.0e38f};
  float lrun[4] = {0.f, 0.f, 0.f, 0.f};

  const int qrow0 = qt * 64 + w * 16 + quad * 4;  // absolute q row of acc element r=0

  for (int t0 = 0; t0 <= qt; t0++) {
    const int kk0 = t0 * 64;
    __syncthreads();
    {  // stage K rows + V transposed (256 threads: 1 row-quarter each = 16 d vals)
      const int trow = tid >> 2;
      const int tpp = tid & 3;
      size_t g = ((size_t)(b * Sc + kk0 + trow)) * Dc + hh * HDc + tpp * 16;
      bf16x8 k0 = *(const bf16x8*)(kx + g);
      bf16x8 k1 = *(const bf16x8*)(kx + g + 8);
      *(bf16x8*)&Ks[trow * PAD + tpp * 16] = k0;
      *(bf16x8*)&Ks[trow * PAD + tpp * 16 + 8] = k1;
      bf16x8 v0 = *(const bf16x8*)(v + g);
      bf16x8 v1 = *(const bf16x8*)(v + g + 8);
#pragma unroll
      for (int j = 0; j < 8; j++) {
        Vt[(tpp * 16 + j) * PAD + trow] = v0[j];
        Vt[(tpp * 16 + 8 + j) * PAD + trow] = v1[j];
      }
    }
    __syncthreads();

    // scores: S = Q @ K^T  (B-frag: n=c -> kk row of Ks, k over d)
    f32x4 sf[4];
#pragma unroll
    for (int nt = 0; nt < 4; nt++) {
      f32x4 a = vzero;
      bf16x8 b0 = *(const bf16x8*)&Ks[(nt * 16 + c) * PAD + quad * 8];
      bf16x8 b1 = *(const bf16x8*)&Ks[(nt * 16 + c) * PAD + 32 + quad * 8];
      a = __builtin_amdgcn_mfma_f32_16x16x32_bf16(qf0, b0, a, 0, 0, 0);
      a = __builtin_amdgcn_mfma_f32_16x16x32_bf16(qf1, b1, a, 0, 0, 0);
      sf[nt] = a;
    }
    if (t0 == qt) {  // diagonal tile causal mask: kk <= q
#pragma unroll
      for (int nt = 0; nt < 4; nt++)
#pragma unroll
        for (int r = 0; r < 4; r++)
          if (kk0 + nt * 16 + c > qrow0 + r) sf[nt][r] = -3.0e38f;
    }

    // online softmax (rows quad*4+r; reduce across the 16 lanes of the quad)
    float mnew[4], alpha[4];
#pragma unroll
    for (int r = 0; r < 4; r++) {
      float mt = fmaxf(fmaxf(sf[0][r], sf[1][r]), fmaxf(sf[2][r], sf[3][r]));
      mt = fmaxf(mt, __shfl_xor(mt, 1, 64));
      mt = fmaxf(mt, __shfl_xor(mt, 2, 64));
      mt = fmaxf(mt, __shfl_xor(mt, 4, 64));
      mt = fmaxf(mt, __shfl_xor(mt, 8, 64));
      mnew[r] = fmaxf(mrun[r], mt);
      alpha[r] = __expf(mrun[r] - mnew[r]);
      mrun[r] = mnew[r];
    }
    float ps[4] = {0.f, 0.f, 0.f, 0.f};
#pragma unroll
    for (int nt = 0; nt < 4; nt++)
#pragma unroll
      for (int r = 0; r < 4; r++) {
        float p = __expf(sf[nt][r] - mnew[r]);
        sf[nt][r] = p;
        ps[r] += p;
      }
#pragma unroll
    for (int r = 0; r < 4; r++) {
      ps[r] += __shfl_xor(ps[r], 1, 64);
      ps[r] += __shfl_xor(ps[r], 2, 64);
      ps[r] += __shfl_xor(ps[r], 4, 64);
      ps[r] += __shfl_xor(ps[r], 8, 64);
      lrun[r] = lrun[r] * alpha[r] + ps[r];
    }
#pragma unroll
    for (int nt = 0; nt < 4; nt++)
#pragma unroll
      for (int r = 0; r < 4; r++) oacc[nt][r] *= alpha[r];

    // P: C-layout -> LDS -> A-layout (wave-private, no barrier needed)
#pragma unroll
    for (int nt = 0; nt < 4; nt++)
#pragma unroll
      for (int r = 0; r < 4; r++)
        Ps[w][(quad * 4 + r) * PAD + nt * 16 + c] = (bf16)sf[nt][r];
    bf16x8 pa0 = *(const bf16x8*)&Ps[w][c * PAD + quad * 8];
    bf16x8 pa1 = *(const bf16x8*)&Ps[w][c * PAD + 32 + quad * 8];

    // O += P @ V  (B-frag: n=c -> d row of Vt, k over kk)
#pragma unroll
    for (int nt = 0; nt < 4; nt++) {
      bf16x8 vb0 = *(const bf16x8*)&Vt[(nt * 16 + c) * PAD + quad * 8];
      bf16x8 vb1 = *(const bf16x8*)&Vt[(nt * 16 + c) * PAD + 32 + quad * 8];
      oacc[nt] = __builtin_amdgcn_mfma_f32_16x16x32_bf16(pa0, vb0, oacc[nt], 0, 0, 0);
      oacc[nt] = __builtin_amdgcn_mfma_f32_16x16x32_bf16(pa1, vb1, oacc[nt], 0, 0, 0);
    }
  }

  // epilogue: rows = qrow0+r, col d = nt*16+c
  float inv[4];
#pragma unroll
  for (int r = 0; r < 4; r++) inv[r] = 1.f / lrun[r];
#pragma unroll
  for (int r = 0; r < 4; r++) {
    const size_t obase = ((size_t)(b * Sc + qrow0 + r)) * Dc + hh * HDc;
#pragma unroll
    for (int nt = 0; nt < 4; nt++)
      o[obase + nt * 16 + c] = (bf16)(oacc[nt][r] * inv[r]);
  }
}

// ---------------------------------------------------------------- elementwise relu (x8)
__global__ __launch_bounds__(256)
void k_relu(const bf16* __restrict__ src, bf16* __restrict__ dst)
{
  int i = blockIdx.x * 256 + threadIdx.x;  // n/8 threads
  bf16x8 v = ((const bf16x8*)src)[i];
  bf16x8 o;
#pragma unroll
  for (int e = 0; e < 8; e++) o[e] = ((float)v[e] > 0.f) ? v[e] : (bf16)0.f;
  ((bf16x8*)dst)[i] = o;
}

// ---------------------------------------------------------------- dp = 2(pred-vf)/M in-place over pred + loss
__global__ __launch_bounds__(256)
void k_dpred(bf16* __restrict__ predDp, const bf16* __restrict__ vf, float* __restrict__ loss)
{
  const size_t idx = (size_t)blockIdx.x * 256 + threadIdx.x;  // NT*M threads
  float e = (float)predDp[idx] - (float)vf[idx];
  predDp[idx] = (bf16)(e * (2.0f / 1024.0f));
  float lacc = e * e;
#pragma unroll
  for (int off = 32; off > 0; off >>= 1) lacc += __shfl_down(lacc, off, 64);
  if ((threadIdx.x & 63) == 0) atomicAdd(loss, lacc);
}

// ---------------------------------------------------------------- colsum: out[c] += sum over a row chunk (parallel over blockIdx.y)
__global__ __launch_bounds__(256)
void k_colsum(const bf16* __restrict__ X, float* __restrict__ out, int C, int rowsPer)
{
  int c = blockIdx.x * 256 + threadIdx.x;
  int r0 = blockIdx.y * rowsPer;
  float s = 0.f;
#pragma unroll 8
  for (int r = r0; r < r0 + rowsPer; r++) s += (float)X[(size_t)r * C + c];
  atomicAdd(&out[c], s);
}

// ---------------------------------------------------------------- dtype-aware param/momentum update -> fp32 d_out
__global__ __launch_bounds__(256)
void k_update_dt(const void* __restrict__ p0w, const void* __restrict__ p0b,
                 const void* __restrict__ p1w, const void* __restrict__ p1b,
                 const void* __restrict__ m0w, const void* __restrict__ m0b,
                 const void* __restrict__ m1w, const void* __restrict__ m1b,
                 const float* __restrict__ g0wF, const float* __restrict__ g0b,
                 const float* __restrict__ g1wF, const float* __restrict__ g1b,
                 const float* __restrict__ loss, const int* __restrict__ flag,
                 float* __restrict__ outP, float* __restrict__ outM)
{
  const int i = blockIdx.x * 256 + threadIdx.x;  // < 2099200 exactly
  const bool upd = (loss[0] >= 0.1f * 1024.f * 4096.f);  // avg_loss >= THRESH
  const bool f32 = (*flag != 0);
  constexpr int W = 1024 * 1024;
  const void *pp, *pm; int j; float g;
  if (i < W) { pp = p0w; pm = m0w; j = i; g = g0wF[i]; }
  else if (i < W + 1024) { j = i - W; pp = p0b; pm = m0b; g = g0b[j]; }
  else if (i < 2 * W + 1024) { j = i - W - 1024; pp = p1w; pm = m1w; g = g1wF[j]; }
  else { j = i - 2 * W - 1024; pp = p1b; pm = m1b; g = g1b[j]; }
  float p = f32 ? ((const float*)pp)[j] : (float)((const bf16*)pp)[j];
  float m = f32 ? ((const float*)pm)[j] : (float)((const bf16*)pm)[j];
  float nm = 0.9f * m - 0.01f * g;
  float np = 0.99f * p + nm;
  outP[i] = upd ? np : p;
  outM[i] = upd ? nm : m;
}

// ================================================================ host
extern "C" void kernel_launch(void* const* d_in, const int* in_sizes, int n_in,
                              void* d_out, int out_size, void* d_ws, size_t ws_size,
                              hipStream_t stream)
{
  (void)in_sizes; (void)n_in; (void)out_size; (void)ws_size;
  const void* x   = d_in[0];
  const void* wq  = d_in[2];
  const void* wk  = d_in[3];
  const void* wv  = d_in[4];
  const void* wo  = d_in[5];
  const void* n1  = d_in[6];
  const void* n2  = d_in[7];
  const void* n3  = d_in[8];
  const void* fw1 = d_in[9];
  const void* fw2 = d_in[10];
  const void* fw3 = d_in[11];
  const void* pkw = d_in[12];
  const void* pkb = d_in[13];
  const void* pvw = d_in[14];
  const void* pvb = d_in[15];
  const void* pqw = d_in[16];
  const void* pqb = d_in[17];
  const void* l0w = d_in[18];
  const void* l0b = d_in[19];
  const void* l1w = d_in[20];
  const void* l1b = d_in[21];
  const void* m0w = d_in[22];
  const void* m0b = d_in[23];
  const void* m1w = d_in[24];
  const void* m1b = d_in[25];

  char* ws = (char*)d_ws;
  size_t off = 0;
  auto alloc = [&](size_t bytes) -> char* {
    char* p = ws + off;
    off += (bytes + 255) & ~(size_t)255;
    return p;
  };

  const size_t DD = (size_t)Dc * Dc;   // 1M elems
  const size_t ND = (size_t)NTc * Dc;  // 4M elems
  const size_t MB8 = 2 * ND;           // 8 MiB
  const size_t M1 = DD;                // 1M elems

  // --- weight region W: 8M bf16 elems (16 MiB), phase-cycled
  bf16* W = (bf16*)alloc(2 * 8 * M1);
  bf16 *wqT = W, *wkT = W + M1, *wvT = W + 2 * M1, *woT = W + 3 * M1;
  bf16 *pqT = W + 4 * M1, *pkT = W + 5 * M1, *pvT = W + 6 * M1, *l0T = W + 7 * M1;
  bf16 *l1T = W + M1;          // staged after wo-GEMM (wkT dead)
  bf16 *l1c = W;               // staged after pred-GEMM (over wqT)
  bf16 *w1T = W + 4 * M1;      // staged after z0-GEMM (pqT..l0T dead)
  bf16 *w2T = W;               // staged after grads (l1c/l1T dead)
  bf16 *w3T = W + 4 * M1;      // staged after ffn1 (w1T dead)

  // --- 5 activation slots, B0..B3 contiguous (s1 spans them at FFN)
  bf16* B0 = (bf16*)alloc(MB8);  // q -> hn2 -> h1r -> h1 -> (s1)
  bf16* B1 = (bf16*)alloc(MB8);  // k -> qlmm -> pred/dp -> (s1)
  bf16* B2 = (bf16*)alloc(MB8);  // v -> kf -> (s1)
  bf16* B3 = (bf16*)alloc(MB8);  // o -> vf -> dz -> (s1)
  bf16* B4 = (bf16*)alloc(MB8);  // hb -> z0 -> hn3
  bf16* s1 = B0;                 // [NT][F] = 32 MiB

  // --- smalls
  float* g0b = (float*)alloc(4 * 1024);
  float* g1b = (float*)alloc(4 * 1024);
  float* lossb = (float*)alloc(256);
  int*   flag  = (int*)alloc(256);
  bf16* n1c = (bf16*)alloc(2 * 1024);
  bf16* n2c = (bf16*)alloc(2 * 1024);
  bf16* n3c = (bf16*)alloc(2 * 1024);
  bf16* bqc = (bf16*)alloc(2 * 1024);
  bf16* bkc = (bf16*)alloc(2 * 1024);
  bf16* bvc = (bf16*)alloc(2 * 1024);
  bf16* b0c = (bf16*)alloc(2 * 1024);
  bf16* b1c = (bf16*)alloc(2 * 1024);

  // --- output regions (fp32)
  float* outX = (float*)d_out;                 // hn(bf16 head), then h2 fp32, then final out fp32
  float* outP = outX + ND;                     // new params (l0w,l0b,l1w,l1b)
  float* outM = outP + (2 * DD + 2048);        // new momenta; hosts g0wF/g1wF pre-update
  float* g0wF = outM;                          // [1M] grad l0_w
  float* g1wF = outM + M1 + 1024;              // [1M] grad l1_w
  bf16*  hn   = (bf16*)outX;                   // bf16 hn in first 8 MiB of outX, dead before h2

  const dim3 tb(32, 8);

  hipMemsetAsync(lossb, 0, sizeof(float), stream);
  hipMemsetAsync(g0b, 0, 4 * 1024, stream);
  hipMemsetAsync(g1b, 0, 4 * 1024, stream);
  k_detect<<<1, 64, 0, stream>>>((const unsigned short*)x, flag);

  // small cvts
  k_cvt<<<1, 256, 0, stream>>>(n1, n1c, 256, flag);
  k_cvt<<<1, 256, 0, stream>>>(n2, n2c, 256, flag);
  k_cvt<<<1, 256, 0, stream>>>(n3, n3c, 256, flag);
  k_cvt<<<1, 256, 0, stream>>>(pqb, bqc, 256, flag);
  k_cvt<<<1, 256, 0, stream>>>(pkb, bkc, 256, flag);
  k_cvt<<<1, 256, 0, stream>>>(pvb, bvc, 256, flag);
  k_cvt<<<1, 256, 0, stream>>>(l0b, b0c, 256, flag);
  k_cvt<<<1, 256, 0, stream>>>(l1b, b1c, 256, flag);

  // phase-1 weight transposes
  k_transpose_dt<<<dim3(32, 32), tb, 0, stream>>>(wq, wqT, Dc, Dc, flag);
  k_transpose_dt<<<dim3(32, 32), tb, 0, stream>>>(wk, wkT, Dc, Dc, flag);
  k_transpose_dt<<<dim3(32, 32), tb, 0, stream>>>(wv, wvT, Dc, Dc, flag);
  k_transpose_dt<<<dim3(32, 32), tb, 0, stream>>>(wo, woT, Dc, Dc, flag);
  k_transpose_dt<<<dim3(32, 32), tb, 0, stream>>>(pqw, pqT, Dc, Mc, flag);
  k_transpose_dt<<<dim3(32, 32), tb, 0, stream>>>(pkw, pkT, Dc, Mc, flag);
  k_transpose_dt<<<dim3(32, 32), tb, 0, stream>>>(pvw, pvT, Dc, Mc, flag);
  k_transpose_dt<<<dim3(32, 32), tb, 0, stream>>>(l0w, l0T, Mc, Mc, flag);

  // ---- attention
  k_rmsnorm_dt<<<NTc, 256, 0, stream>>>(x, n1c, hn, flag);
  k_gemm<EPI_BF16><<<dim3(8, 32), 256, 0, stream>>>(hn, wqT, NTc, Dc, Dc, nullptr, B0, nullptr, nullptr, nullptr, nullptr, nullptr);
  k_gemm<EPI_BF16><<<dim3(8, 32), 256, 0, stream>>>(hn, wkT, NTc, Dc, Dc, nullptr, B1, nullptr, nullptr, nullptr, nullptr, nullptr);
  k_gemm<EPI_BF16><<<dim3(8, 32), 256, 0, stream>>>(hn, wvT, NTc, Dc, Dc, nullptr, B2, nullptr, nullptr, nullptr, nullptr, nullptr);
  k_rope<<<256, 256, 0, stream>>>(B0, B1);
  k_attn<<<1024, 256, 0, stream>>>(B0, B1, B2, B3);
  k_gemm<EPI_RESX_BF16><<<dim3(8, 32), 256, 0, stream>>>(B3, woT, NTc, Dc, Dc, nullptr, B4, nullptr, nullptr, nullptr, x, flag);  // hb -> B4
  k_transpose_dt<<<dim3(32, 32), tb, 0, stream>>>(l1w, l1T, Mc, Mc, flag);

  // ---- LMM forward
  k_rmsnorm_b<<<NTc, 256, 0, stream>>>(B4, n2c, B0);   // hn2 -> B0
  k_gemm<EPI_BIAS_BF16><<<dim3(8, 32), 256, 0, stream>>>(B0, pqT, NTc, Mc, Dc, nullptr, B1, bqc, nullptr, nullptr, nullptr, nullptr);  // qlmm
  k_gemm<EPI_BIAS_BF16><<<dim3(8, 32), 256, 0, stream>>>(B0, pkT, NTc, Mc, Dc, nullptr, B2, bkc, nullptr, nullptr, nullptr, nullptr);  // kf
  k_gemm<EPI_BIAS_BF16><<<dim3(8, 32), 256, 0, stream>>>(B0, pvT, NTc, Mc, Dc, nullptr, B3, bvc, nullptr, nullptr, nullptr, nullptr);  // vf
  k_gemm<EPI_BIAS_RELU_BF16><<<dim3(8, 32), 256, 0, stream>>>(B1, l0T, NTc, Mc, Mc, nullptr, B0, b0c, nullptr, nullptr, nullptr, nullptr);  // h1r
  // h2 = h1r@l1T + l1b + hb -> fp32 in outX (overwrites bf16 hn region; hn is dead)
  k_gemm<EPI_BIAS_RESB_F32><<<dim3(8, 32), 256, 0, stream>>>(B0, l1T, NTc, Mc, Mc, outX, nullptr, b1c, B4, nullptr, nullptr, nullptr);

  // ---- LMM loss fwd/bwd
  k_gemm<EPI_BIAS_BF16><<<dim3(8, 32), 256, 0, stream>>>(B2, l0T, NTc, Mc, Mc, nullptr, B4, b0c, nullptr, nullptr, nullptr, nullptr);  // z0 -> B4
  k_transpose_dt<<<dim3(128, 32), tb, 0, stream>>>(fw1, w1T, Dc, Fc, flag);     // stage w1T (pqT..l0T dead)
  k_relu<<<2048, 256, 0, stream>>>(B4, B0);            // h1 -> B0
  k_gemm<EPI_BIAS_BF16><<<dim3(8, 32), 256, 0, stream>>>(B0, l1T, NTc, Mc, Mc, nullptr, B1, b1c, nullptr, nullptr, nullptr, nullptr);  // pred -> B1
  k_cvt<<<1024, 256, 0, stream>>>(l1w, l1c, (int)(DD / 4), flag);
  k_dpred<<<16384, 256, 0, stream>>>(B1, B3, lossb);   // dp in-place over pred
  k_gemm<EPI_DZ_BF16><<<dim3(8, 32), 256, 0, stream>>>(B1, l1c, NTc, Mc, Mc, nullptr, B3, nullptr, B4, nullptr, nullptr, nullptr);     // dz -> B3
  k_gemm_tn<<<dim3(8, 8), 256, 0, stream>>>(B0, B1, NTc, g1wF);   // g1w = h1^T dp (fp32)
  k_gemm_tn<<<dim3(8, 8), 256, 0, stream>>>(B2, B3, NTc, g0wF);   // g0w = kf^T dz (fp32)
  k_colsum<<<dim3(4, 32), 256, 0, stream>>>(B1, g1b, Mc, NTc / 32);
  k_colsum<<<dim3(4, 32), 256, 0, stream>>>(B3, g0b, Mc, NTc / 32);
  k_update_dt<<<8200, 256, 0, stream>>>(l0w, l0b, l1w, l1b, m0w, m0b, m1w, m1b,
                                        g0wF, g0b, g1wF, g1b, lossb, flag, outP, outM);

  // ---- FFN (all B-slots free; h2 fp32 in outX)
  k_transpose_dt<<<dim3(128, 32), tb, 0, stream>>>(fw2, w2T, Dc, Fc, flag);     // stage w2T (l1c/l1T dead)
  k_rmsnorm_f<<<NTc, 256, 0, stream>>>(outX, n3c, B4); // hn3 -> B4
  k_gemm<EPI_BF16><<<dim3(32, 32), 256, 0, stream>>>(B4, w1T, NTc, Fc, Dc, nullptr, s1, nullptr, nullptr, nullptr, nullptr, nullptr);
  k_transpose_dt<<<dim3(32, 128), tb, 0, stream>>>(fw3, w3T, Fc, Dc, flag);     // stage w3T (w1T dead)
  k_gemm<EPI_SILU_BF16><<<dim3(32, 32), 256, 0, stream>>>(B4, w2T, NTc, Fc, Dc, nullptr, s1, nullptr, s1, nullptr, nullptr, nullptr);
  // out = s1@w3T + h2  (fp32 in-place over outX)
  k_gemm<EPI_RESF_F32><<<dim3(8, 32), 256, 0, stream>>>(s1, w3T, NTc, Dc, Fc, outX, nullptr, nullptr, nullptr, outX, nullptr, nullptr);
}

// Round 8
// 1340.518 us; speedup vs baseline: 3.3966x; 1.6331x over previous
//
#include <hip/hip_runtime.h>
#include <cstdint>
#include <cstddef>

typedef __bf16 bf16;
typedef __bf16 bf16x2 __attribute__((ext_vector_type(2)));
typedef __bf16 bf16x4 __attribute__((ext_vector_type(4)));
typedef __bf16 bf16x8 __attribute__((ext_vector_type(8)));
typedef float  f32x4  __attribute__((ext_vector_type(4)));
typedef __attribute__((address_space(1))) unsigned int u32_g;
typedef __attribute__((address_space(3))) unsigned int u32_l;

#define DI __device__ __forceinline__

constexpr int Bc = 2, Sc = 2048, Dc = 1024, Hc = 16, HDc = 64, Fc = 4096, Mc = 1024;
constexpr int NTc = Bc * Sc;  // 4096 tokens

DI void llds16(const bf16* g, bf16* l) {
  __builtin_amdgcn_global_load_lds((const u32_g*)g, (u32_l*)l, 16, 0, 0);
}
DI f32x4 cvt4(bf16x4 a) {
  f32x4 r; r[0] = (float)a[0]; r[1] = (float)a[1]; r[2] = (float)a[2]; r[3] = (float)a[3];
  return r;
}

// ---------------------------------------------------------------- dtype detector (inputs)
__global__ void k_detect(const unsigned short* __restrict__ x, int* __restrict__ flag)
{
  const int tid = threadIdx.x;  // 64
  int cnt = 0;
#pragma unroll
  for (int i = 0; i < 8; i++) {
    unsigned short h = x[tid * 8 + i];
    int e = (h >> 7) & 0xFF;
    if (e < 96 || e > 160) cnt++;
  }
#pragma unroll
  for (int off = 32; off > 0; off >>= 1) cnt += __shfl_down(cnt, off, 64);
  if (tid == 0) *flag = (cnt > 32) ? 1 : 0;
}

// ---------------------------------------------------------------- dtype-aware convert to bf16
__global__ __launch_bounds__(256)
void k_cvt(const void* __restrict__ src, bf16* __restrict__ dst, int n4, const int* __restrict__ flag)
{
  int i = blockIdx.x * 256 + threadIdx.x;
  if (i >= n4) return;
  bf16x4 o;
  if (*flag) {
    f32x4 v = ((const f32x4*)src)[i];
    o[0] = (bf16)v[0]; o[1] = (bf16)v[1]; o[2] = (bf16)v[2]; o[3] = (bf16)v[3];
  } else {
    o = ((const bf16x4*)src)[i];
  }
  ((bf16x4*)dst)[i] = o;
}

// ---------------------------------------------------------------- dtype-aware transpose [R][C] -> bf16 [C][R]
__global__ void k_transpose_dt(const void* __restrict__ src, bf16* __restrict__ dst,
                               int R, int C, const int* __restrict__ flag)
{
  __shared__ bf16 tile[32][33];
  const int c0 = blockIdx.x * 32, r0 = blockIdx.y * 32;
  const int tx = threadIdx.x, ty = threadIdx.y;
  const bool f32 = (*flag != 0);
  for (int i = ty; i < 32; i += 8) {
    size_t idx = (size_t)(r0 + i) * C + (c0 + tx);
    tile[i][tx] = f32 ? (bf16)((const float*)src)[idx] : ((const bf16*)src)[idx];
  }
  __syncthreads();
  for (int i = ty; i < 32; i += 8)
    dst[(size_t)(c0 + i) * R + (r0 + tx)] = tile[tx][i];
}

// ---------------------------------------------------------------- GEMM (NT): C[M][N] = A[M][K] * Bt[N][K]^T
enum EpiMode { EPI_BF16 = 0, EPI_BIAS_BF16, EPI_BIAS_RELU_BF16, EPI_BIAS_RESB_F32,
               EPI_SILU_BF16, EPI_DZ_BF16, EPI_RESX_BF16, EPI_RESF_F32 };

template <int EPI>
__global__ __launch_bounds__(256)
void k_gemm(const bf16* __restrict__ A, const bf16* __restrict__ Bt,
            int Mr, int Nr, int Kr,
            float* outF, bf16* outB,
            const bf16* __restrict__ bias, const bf16* auxB,
            const float* resF,
            const void* __restrict__ resX, const int* __restrict__ flag)
{
  __shared__ bf16 As[128 * 32];
  __shared__ bf16 Bs[128 * 32];
  const int tid = threadIdx.x;
  const int w = tid >> 6, l = tid & 63;
  const int wr = w >> 1, wc = w & 1;
  const int row0 = blockIdx.y * 128, col0 = blockIdx.x * 128;

  const f32x4 vzero = {0.f, 0.f, 0.f, 0.f};
  f32x4 acc[4][4];
#pragma unroll
  for (int i = 0; i < 4; i++)
#pragma unroll
    for (int j = 0; j < 4; j++) acc[i][j] = vzero;

  const bf16* Ag = A + (size_t)(row0 + w * 16 + (l >> 2)) * Kr + ((l & 3) << 3);
  const bf16* Bg = Bt + (size_t)(col0 + w * 16 + (l >> 2)) * Kr + ((l & 3) << 3);
  bf16* AsW = &As[w * 512];
  bf16* BsW = &Bs[w * 512];
  const size_t rowHop = (size_t)64 * Kr;

  for (int k0 = 0; k0 < Kr; k0 += 32) {
    __syncthreads();
    llds16(Ag + k0, AsW);
    llds16(Ag + rowHop + k0, AsW + 2048);
    llds16(Bg + k0, BsW);
    llds16(Bg + rowHop + k0, BsW + 2048);
    __syncthreads();
    bf16x8 af[4], bfr[4];
#pragma unroll
    for (int mt = 0; mt < 4; mt++)
      af[mt] = *(const bf16x8*)&As[(wr * 64 + mt * 16 + (l & 15)) * 32 + (l >> 4) * 8];
#pragma unroll
    for (int nt = 0; nt < 4; nt++)
      bfr[nt] = *(const bf16x8*)&Bs[(wc * 64 + nt * 16 + (l & 15)) * 32 + (l >> 4) * 8];
#pragma unroll
    for (int mt = 0; mt < 4; mt++)
#pragma unroll
      for (int nt = 0; nt < 4; nt++)
        acc[mt][nt] = __builtin_amdgcn_mfma_f32_16x16x32_bf16(af[mt], bfr[nt], acc[mt][nt], 0, 0, 0);
  }

  const bool f32res = (EPI == EPI_RESX_BF16) ? (*flag != 0) : false;
  // C/D layout (verified m89/m91): col = lane&15, row = (lane>>4)*4 + reg
#pragma unroll
  for (int mt = 0; mt < 4; mt++) {
    const int rowb = row0 + wr * 64 + mt * 16 + ((l >> 4) << 2);
#pragma unroll
    for (int nt = 0; nt < 4; nt++) {
      const int col = col0 + wc * 64 + nt * 16 + (l & 15);
#pragma unroll
      for (int r = 0; r < 4; r++) {
        const size_t idx = (size_t)(rowb + r) * Nr + col;
        float v = acc[mt][nt][r];
        if (EPI == EPI_BF16) { outB[idx] = (bf16)v; }
        else if (EPI == EPI_BIAS_BF16) { outB[idx] = (bf16)(v + (float)bias[col]); }
        else if (EPI == EPI_BIAS_RELU_BF16) { outB[idx] = (bf16)fmaxf(v + (float)bias[col], 0.f); }
        else if (EPI == EPI_BIAS_RESB_F32) { outF[idx] = v + (float)bias[col] + (float)auxB[idx]; }
        else if (EPI == EPI_SILU_BF16) {   // in place: outB == auxB, same idx
          float s1v = (float)auxB[idx];
          float sl = s1v / (1.f + __expf(-s1v));
          outB[idx] = (bf16)(sl * v);
        }
        else if (EPI == EPI_DZ_BF16) {     // mask by relu'(z0) at same idx
          float zv = (float)auxB[idx];
          outB[idx] = (bf16)(zv > 0.f ? v : 0.f);
        }
        else if (EPI == EPI_RESX_BF16) {   // residual from raw input (dtype-aware)
          float rv = f32res ? ((const float*)resX)[idx] : (float)((const bf16*)resX)[idx];
          outB[idx] = (bf16)(v + rv);
        }
        else if (EPI == EPI_RESF_F32) {    // in place fp32: outF == resF, same idx
          outF[idx] = v + resF[idx];
        }
      }
    }
  }
}

// ---------------------------------------------------------------- GEMM (TN): C[i][j] = sum_t X[t][i]*Y[t][j] -> fp32
__global__ __launch_bounds__(256)
void k_gemm_tn(const bf16* __restrict__ X, const bf16* __restrict__ Y, int Kt,
               float* __restrict__ out)
{
  __shared__ bf16 As[128 * 36];
  __shared__ bf16 Bs[128 * 36];
  const int tid = threadIdx.x;
  const int w = tid >> 6, l = tid & 63;
  const int wr = w >> 1, wc = w & 1;
  const int row0 = blockIdx.y * 128, col0 = blockIdx.x * 128;
  const int iofs = (tid & 15) * 8;   // 0..120
  const int tp   = (tid >> 4) * 2;   // 0..30

  const f32x4 vzero = {0.f, 0.f, 0.f, 0.f};
  f32x4 acc[4][4];
#pragma unroll
  for (int i = 0; i < 4; i++)
#pragma unroll
    for (int j = 0; j < 4; j++) acc[i][j] = vzero;

  for (int t0 = 0; t0 < Kt; t0 += 32) {
    __syncthreads();
    bf16x8 a0 = *(const bf16x8*)&X[(size_t)(t0 + tp) * 1024 + row0 + iofs];
    bf16x8 a1 = *(const bf16x8*)&X[(size_t)(t0 + tp + 1) * 1024 + row0 + iofs];
    bf16x8 b0 = *(const bf16x8*)&Y[(size_t)(t0 + tp) * 1024 + col0 + iofs];
    bf16x8 b1 = *(const bf16x8*)&Y[(size_t)(t0 + tp + 1) * 1024 + col0 + iofs];
#pragma unroll
    for (int e = 0; e < 8; e++) {
      bf16x2 pa; pa[0] = a0[e]; pa[1] = a1[e];
      bf16x2 pb; pb[0] = b0[e]; pb[1] = b1[e];
      *(bf16x2*)&As[(iofs + e) * 36 + tp] = pa;
      *(bf16x2*)&Bs[(iofs + e) * 36 + tp] = pb;
    }
    __syncthreads();
    bf16x8 af[4], bfr[4];
#pragma unroll
    for (int mt = 0; mt < 4; mt++) {
      const int base = (wr * 64 + mt * 16 + (l & 15)) * 36 + (l >> 4) * 8;
      bf16x4 lo = *(const bf16x4*)&As[base];
      bf16x4 hi = *(const bf16x4*)&As[base + 4];
#pragma unroll
      for (int e = 0; e < 4; e++) { af[mt][e] = lo[e]; af[mt][4 + e] = hi[e]; }
    }
#pragma unroll
    for (int nt = 0; nt < 4; nt++) {
      const int base = (wc * 64 + nt * 16 + (l & 15)) * 36 + (l >> 4) * 8;
      bf16x4 lo = *(const bf16x4*)&Bs[base];
      bf16x4 hi = *(const bf16x4*)&Bs[base + 4];
#pragma unroll
      for (int e = 0; e < 4; e++) { bfr[nt][e] = lo[e]; bfr[nt][4 + e] = hi[e]; }
    }
#pragma unroll
    for (int mt = 0; mt < 4; mt++)
#pragma unroll
      for (int nt = 0; nt < 4; nt++)
        acc[mt][nt] = __builtin_amdgcn_mfma_f32_16x16x32_bf16(af[mt], bfr[nt], acc[mt][nt], 0, 0, 0);
  }

#pragma unroll
  for (int mt = 0; mt < 4; mt++) {
    const int rowb = row0 + wr * 64 + mt * 16 + ((l >> 4) << 2);
#pragma unroll
    for (int nt = 0; nt < 4; nt++) {
      const int col = col0 + wc * 64 + nt * 16 + (l & 15);
#pragma unroll
      for (int r = 0; r < 4; r++)
        out[(size_t)(rowb + r) * 1024 + col] = acc[mt][nt][r];
    }
  }
}

// ---------------------------------------------------------------- RMSNorm variants
__global__ __launch_bounds__(256)
void k_rmsnorm_dt(const void* __restrict__ x, const bf16* __restrict__ w, bf16* __restrict__ out,
                  const int* __restrict__ flag)
{
  const int row = blockIdx.x;
  const int tid = threadIdx.x;
  f32x4 xv;
  if (*flag) xv = *(const f32x4*)((const float*)x + (size_t)row * Dc + tid * 4);
  else       xv = cvt4(*(const bf16x4*)((const bf16*)x + (size_t)row * Dc + tid * 4));
  float ss = xv[0] * xv[0] + xv[1] * xv[1] + xv[2] * xv[2] + xv[3] * xv[3];
#pragma unroll
  for (int off = 32; off > 0; off >>= 1) ss += __shfl_down(ss, off, 64);
  __shared__ float part[4];
  if ((tid & 63) == 0) part[tid >> 6] = ss;
  __syncthreads();
  float tot = part[0] + part[1] + part[2] + part[3];
  float inv = 1.f / (sqrtf(tot) * 0.03125f + 1e-8f);
  bf16x4 wb = *(const bf16x4*)(w + tid * 4);
  bf16x4 ov;
  ov[0] = (bf16)((float)wb[0] * xv[0] * inv);
  ov[1] = (bf16)((float)wb[1] * xv[1] * inv);
  ov[2] = (bf16)((float)wb[2] * xv[2] * inv);
  ov[3] = (bf16)((float)wb[3] * xv[3] * inv);
  *(bf16x4*)(out + (size_t)row * Dc + tid * 4) = ov;
}

__global__ __launch_bounds__(256)
void k_rmsnorm_b(const bf16* __restrict__ x, const bf16* __restrict__ w, bf16* __restrict__ out)
{
  const int row = blockIdx.x;
  const int tid = threadIdx.x;
  f32x4 xv = cvt4(*(const bf16x4*)(x + (size_t)row * Dc + tid * 4));
  float ss = xv[0] * xv[0] + xv[1] * xv[1] + xv[2] * xv[2] + xv[3] * xv[3];
#pragma unroll
  for (int off = 32; off > 0; off >>= 1) ss += __shfl_down(ss, off, 64);
  __shared__ float part[4];
  if ((tid & 63) == 0) part[tid >> 6] = ss;
  __syncthreads();
  float tot = part[0] + part[1] + part[2] + part[3];
  float inv = 1.f / (sqrtf(tot) * 0.03125f + 1e-8f);
  bf16x4 wb = *(const bf16x4*)(w + tid * 4);
  bf16x4 ov;
  ov[0] = (bf16)((float)wb[0] * xv[0] * inv);
  ov[1] = (bf16)((float)wb[1] * xv[1] * inv);
  ov[2] = (bf16)((float)wb[2] * xv[2] * inv);
  ov[3] = (bf16)((float)wb[3] * xv[3] * inv);
  *(bf16x4*)(out + (size_t)row * Dc + tid * 4) = ov;
}

__global__ __launch_bounds__(256)
void k_rmsnorm_f(const float* __restrict__ x, const bf16* __restrict__ w, bf16* __restrict__ out)
{
  const int row = blockIdx.x;
  const int tid = threadIdx.x;
  f32x4 xv = *(const f32x4*)(x + (size_t)row * Dc + tid * 4);
  float ss = xv[0] * xv[0] + xv[1] * xv[1] + xv[2] * xv[2] + xv[3] * xv[3];
#pragma unroll
  for (int off = 32; off > 0; off >>= 1) ss += __shfl_down(ss, off, 64);
  __shared__ float part[4];
  if ((tid & 63) == 0) part[tid >> 6] = ss;
  __syncthreads();
  float tot = part[0] + part[1] + part[2] + part[3];
  float inv = 1.f / (sqrtf(tot) * 0.03125f + 1e-8f);
  bf16x4 wb = *(const bf16x4*)(w + tid * 4);
  bf16x4 ov;
  ov[0] = (bf16)((float)wb[0] * xv[0] * inv);
  ov[1] = (bf16)((float)wb[1] * xv[1] * inv);
  ov[2] = (bf16)((float)wb[2] * xv[2] * inv);
  ov[3] = (bf16)((float)wb[3] * xv[3] * inv);
  *(bf16x4*)(out + (size_t)row * Dc + tid * 4) = ov;
}

// ---------------------------------------------------------------- RoPE in-place on bf16 q,k
__global__ __launch_bounds__(256)
void k_rope(bf16* __restrict__ q, bf16* __restrict__ kx)
{
  const int idx = blockIdx.x * 256 + threadIdx.x;  // NT*H = 65536
  const int t = idx >> 4, hh = idx & 15;
  const int s = t & (Sc - 1);
  float sn[32], cs[32];
#pragma unroll
  for (int i = 0; i < 32; i++) {
    float f = expf(-(float)i * 0.28782313662425574f);  // ln(10000)/32
    float ang = (float)s * f;
    sn[i] = sinf(ang);
    cs[i] = cosf(ang);
  }
  for (int pass = 0; pass < 2; pass++) {
    bf16* p = (pass ? kx : q) + (size_t)t * Dc + hh * HDc;
    float xb[64], ob[64];
#pragma unroll
    for (int j = 0; j < 16; j++) *(f32x4*)&xb[j * 4] = cvt4(*(const bf16x4*)(p + j * 4));
#pragma unroll
    for (int i = 0; i < 32; i++) {
      float x1 = xb[2 * i], x2 = xb[2 * i + 1];
      ob[i] = x1 * cs[i] - x2 * sn[i];
      ob[32 + i] = x1 * sn[i] + x2 * cs[i];
    }
#pragma unroll
    for (int j = 0; j < 16; j++) {
      bf16x4 o4;
      o4[0] = (bf16)ob[j * 4]; o4[1] = (bf16)ob[j * 4 + 1];
      o4[2] = (bf16)ob[j * 4 + 2]; o4[3] = (bf16)ob[j * 4 + 3];
      *(bf16x4*)(p + j * 4) = o4;
    }
  }
}

// ---------------------------------------------------------------- MFMA flash attention
__global__ __launch_bounds__(256)
void k_attn(const bf16* __restrict__ q, const bf16* __restrict__ kx,
            const bf16* __restrict__ v, bf16* __restrict__ o)
{
  constexpr int PAD = 72;
  __shared__ bf16 Ks[64 * PAD];
  __shared__ bf16 Vt[64 * PAD];        // Vt[d][kk]
  __shared__ bf16 Ps[4][16 * PAD];     // per-wave P buffer

  const int blk = blockIdx.x;
  const int qt = blk & 31;
  const int bh = blk >> 5;
  const int b = bh >> 4, hh = bh & 15;
  const int tid = threadIdx.x;
  const int w = tid >> 6, l = tid & 63;
  const int quad = l >> 4, c = l & 15;

  // Q A-frags (m = c, k = quad*8+j), pre-scaled by 1/sqrt(HD)=0.125 (exact in bf16)
  const int qrow = qt * 64 + w * 16 + c;
  const size_t qbase = ((size_t)(b * Sc + qrow)) * Dc + hh * HDc;
  bf16x8 qf0 = *(const bf16x8*)(q + qbase + quad * 8);
  bf16x8 qf1 = *(const bf16x8*)(q + qbase + 32 + quad * 8);
#pragma unroll
  for (int j = 0; j < 8; j++) {
    qf0[j] = (bf16)((float)qf0[j] * 0.125f);
    qf1[j] = (bf16)((float)qf1[j] * 0.125f);
  }

  const f32x4 vzero = {0.f, 0.f, 0.f, 0.f};
  f32x4 oacc[4];
#pragma unroll
  for (int nt = 0; nt < 4; nt++) oacc[nt] = vzero;
  float mrun[4] = {-3.0e38f, -3.0e38f, -3.0e38f, -3.0e38f};
  float lrun[4] = {0.f, 0.f, 0.f, 0.f};

  const int qrow0 = qt * 64 + w * 16 + quad * 4;  // absolute q row of acc element r=0

  for (int t0 = 0; t0 <= qt; t0++) {
    const int kk0 = t0 * 64;
    __syncthreads();
    {  // stage K rows + V transposed
      const int trow = tid >> 2;
      const int tpp = tid & 3;
      size_t g = ((size_t)(b * Sc + kk0 + trow)) * Dc + hh * HDc + tpp * 16;
      bf16x8 k0 = *(const bf16x8*)(kx + g);
      bf16x8 k1 = *(const bf16x8*)(kx + g + 8);
      *(bf16x8*)&Ks[trow * PAD + tpp * 16] = k0;
      *(bf16x8*)&Ks[trow * PAD + tpp * 16 + 8] = k1;
      bf16x8 v0 = *(const bf16x8*)(v + g);
      bf16x8 v1 = *(const bf16x8*)(v + g + 8);
#pragma unroll
      for (int j = 0; j < 8; j++) {
        Vt[(tpp * 16 + j) * PAD + trow] = v0[j];
        Vt[(tpp * 16 + 8 + j) * PAD + trow] = v1[j];
      }
    }
    __syncthreads();

    // scores: S = Q @ K^T
    f32x4 sf[4];
#pragma unroll
    for (int nt = 0; nt < 4; nt++) {
      f32x4 a = vzero;
      bf16x8 b0 = *(const bf16x8*)&Ks[(nt * 16 + c) * PAD + quad * 8];
      bf16x8 b1 = *(const bf16x8*)&Ks[(nt * 16 + c) * PAD + 32 + quad * 8];
      a = __builtin_amdgcn_mfma_f32_16x16x32_bf16(qf0, b0, a, 0, 0, 0);
      a = __builtin_amdgcn_mfma_f32_16x16x32_bf16(qf1, b1, a, 0, 0, 0);
      sf[nt] = a;
    }
    if (t0 == qt) {  // diagonal tile causal mask: kk <= q
#pragma unroll
      for (int nt = 0; nt < 4; nt++)
#pragma unroll
        for (int r = 0; r < 4; r++)
          if (kk0 + nt * 16 + c > qrow0 + r) sf[nt][r] = -3.0e38f;
    }

    // online softmax
    float mnew[4], alpha[4];
#pragma unroll
    for (int r = 0; r < 4; r++) {
      float mt = fmaxf(fmaxf(sf[0][r], sf[1][r]), fmaxf(sf[2][r], sf[3][r]));
      mt = fmaxf(mt, __shfl_xor(mt, 1, 64));
      mt = fmaxf(mt, __shfl_xor(mt, 2, 64));
      mt = fmaxf(mt, __shfl_xor(mt, 4, 64));
      mt = fmaxf(mt, __shfl_xor(mt, 8, 64));
      mnew[r] = fmaxf(mrun[r], mt);
      alpha[r] = __expf(mrun[r] - mnew[r]);
      mrun[r] = mnew[r];
    }
    float ps[4] = {0.f, 0.f, 0.f, 0.f};
#pragma unroll
    for (int nt = 0; nt < 4; nt++)
#pragma unroll
      for (int r = 0; r < 4; r++) {
        float p = __expf(sf[nt][r] - mnew[r]);
        sf[nt][r] = p;
        ps[r] += p;
      }
#pragma unroll
    for (int r = 0; r < 4; r++) {
      ps[r] += __shfl_xor(ps[r], 1, 64);
      ps[r] += __shfl_xor(ps[r], 2, 64);
      ps[r] += __shfl_xor(ps[r], 4, 64);
      ps[r] += __shfl_xor(ps[r], 8, 64);
      lrun[r] = lrun[r] * alpha[r] + ps[r];
    }
#pragma unroll
    for (int nt = 0; nt < 4; nt++)
#pragma unroll
      for (int r = 0; r < 4; r++) oacc[nt][r] *= alpha[r];

    // P: C-layout -> LDS -> A-layout (wave-private)
#pragma unroll
    for (int nt = 0; nt < 4; nt++)
#pragma unroll
      for (int r = 0; r < 4; r++)
        Ps[w][(quad * 4 + r) * PAD + nt * 16 + c] = (bf16)sf[nt][r];
    bf16x8 pa0 = *(const bf16x8*)&Ps[w][c * PAD + quad * 8];
    bf16x8 pa1 = *(const bf16x8*)&Ps[w][c * PAD + 32 + quad * 8];

    // O += P @ V
#pragma unroll
    for (int nt = 0; nt < 4; nt++) {
      bf16x8 vb0 = *(const bf16x8*)&Vt[(nt * 16 + c) * PAD + quad * 8];
      bf16x8 vb1 = *(const bf16x8*)&Vt[(nt * 16 + c) * PAD + 32 + quad * 8];
      oacc[nt] = __builtin_amdgcn_mfma_f32_16x16x32_bf16(pa0, vb0, oacc[nt], 0, 0, 0);
      oacc[nt] = __builtin_amdgcn_mfma_f32_16x16x32_bf16(pa1, vb1, oacc[nt], 0, 0, 0);
    }
  }

  float inv[4];
#pragma unroll
  for (int r = 0; r < 4; r++) inv[r] = 1.f / lrun[r];
#pragma unroll
  for (int r = 0; r < 4; r++) {
    const size_t obase = ((size_t)(b * Sc + qrow0 + r)) * Dc + hh * HDc;
#pragma unroll
    for (int nt = 0; nt < 4; nt++)
      o[obase + nt * 16 + c] = (bf16)(oacc[nt][r] * inv[r]);
  }
}

// ---------------------------------------------------------------- elementwise relu (x8)
__global__ __launch_bounds__(256)
void k_relu(const bf16* __restrict__ src, bf16* __restrict__ dst)
{
  int i = blockIdx.x * 256 + threadIdx.x;  // n/8 threads
  bf16x8 v = ((const bf16x8*)src)[i];
  bf16x8 o;
#pragma unroll
  for (int e = 0; e < 8; e++) o[e] = ((float)v[e] > 0.f) ? v[e] : (bf16)0.f;
  ((bf16x8*)dst)[i] = o;
}

// ---------------------------------------------------------------- dp = 2(pred-vf)/M in-place + loss
// grid-stride, bf16x8 vector io, ONE atomicAdd per block (G12: 65536 -> 256 atomics)
__global__ __launch_bounds__(256)
void k_dpred(bf16* __restrict__ predDp, const bf16* __restrict__ vf, float* __restrict__ loss)
{
  __shared__ float red[4];
  const int tid = threadIdx.x;
  const size_t n8 = (size_t)NTc * Mc / 8;
  float lacc = 0.f;
  for (size_t i = (size_t)blockIdx.x * 256 + tid; i < n8; i += (size_t)gridDim.x * 256) {
    bf16x8 p8 = ((const bf16x8*)predDp)[i];
    bf16x8 v8 = ((const bf16x8*)vf)[i];
    bf16x8 d8;
#pragma unroll
    for (int e = 0; e < 8; e++) {
      float df = (float)p8[e] - (float)v8[e];
      lacc += df * df;
      d8[e] = (bf16)(df * (2.0f / 1024.0f));
    }
    ((bf16x8*)predDp)[i] = d8;
  }
#pragma unroll
  for (int off = 32; off > 0; off >>= 1) lacc += __shfl_down(lacc, off, 64);
  if ((tid & 63) == 0) red[tid >> 6] = lacc;
  __syncthreads();
  if (tid == 0) atomicAdd(loss, red[0] + red[1] + red[2] + red[3]);
}

// ---------------------------------------------------------------- colsum: out[c] += sum over a row chunk
__global__ __launch_bounds__(256)
void k_colsum(const bf16* __restrict__ X, float* __restrict__ out, int C, int rowsPer)
{
  int c = blockIdx.x * 256 + threadIdx.x;
  int r0 = blockIdx.y * rowsPer;
  float s = 0.f;
#pragma unroll 8
  for (int r = r0; r < r0 + rowsPer; r++) s += (float)X[(size_t)r * C + c];
  atomicAdd(&out[c], s);
}

// ---------------------------------------------------------------- dtype-aware param/momentum update -> fp32 d_out
__global__ __launch_bounds__(256)
void k_update_dt(const void* __restrict__ p0w, const void* __restrict__ p0b,
                 const void* __restrict__ p1w, const void* __restrict__ p1b,
                 const void* __restrict__ m0w, const void* __restrict__ m0b,
                 const void* __restrict__ m1w, const void* __restrict__ m1b,
                 const float* __restrict__ g0wF, const float* __restrict__ g0b,
                 const float* __restrict__ g1wF, const float* __restrict__ g1b,
                 const float* __restrict__ loss, const int* __restrict__ flag,
                 float* __restrict__ outP, float* __restrict__ outM)
{
  const int i = blockIdx.x * 256 + threadIdx.x;  // < 2099200 exactly
  const bool upd = (loss[0] >= 0.1f * 1024.f * 4096.f);  // avg_loss >= THRESH
  const bool f32 = (*flag != 0);
  constexpr int W = 1024 * 1024;
  const void *pp, *pm; int j; float g;
  if (i < W) { pp = p0w; pm = m0w; j = i; g = g0wF[i]; }
  else if (i < W + 1024) { j = i - W; pp = p0b; pm = m0b; g = g0b[j]; }
  else if (i < 2 * W + 1024) { j = i - W - 1024; pp = p1w; pm = m1w; g = g1wF[j]; }
  else { j = i - 2 * W - 1024; pp = p1b; pm = m1b; g = g1b[j]; }
  float p = f32 ? ((const float*)pp)[j] : (float)((const bf16*)pp)[j];
  float m = f32 ? ((const float*)pm)[j] : (float)((const bf16*)pm)[j];
  float nm = 0.9f * m - 0.01f * g;
  float np = 0.99f * p + nm;
  outP[i] = upd ? np : p;
  outM[i] = upd ? nm : m;
}

// ================================================================ host
extern "C" void kernel_launch(void* const* d_in, const int* in_sizes, int n_in,
                              void* d_out, int out_size, void* d_ws, size_t ws_size,
                              hipStream_t stream)
{
  (void)in_sizes; (void)n_in; (void)out_size; (void)ws_size;
  const void* x   = d_in[0];
  const void* wq  = d_in[2];
  const void* wk  = d_in[3];
  const void* wv  = d_in[4];
  const void* wo  = d_in[5];
  const void* n1  = d_in[6];
  const void* n2  = d_in[7];
  const void* n3  = d_in[8];
  const void* fw1 = d_in[9];
  const void* fw2 = d_in[10];
  const void* fw3 = d_in[11];
  const void* pkw = d_in[12];
  const void* pkb = d_in[13];
  const void* pvw = d_in[14];
  const void* pvb = d_in[15];
  const void* pqw = d_in[16];
  const void* pqb = d_in[17];
  const void* l0w = d_in[18];
  const void* l0b = d_in[19];
  const void* l1w = d_in[20];
  const void* l1b = d_in[21];
  const void* m0w = d_in[22];
  const void* m0b = d_in[23];
  const void* m1w = d_in[24];
  const void* m1b = d_in[25];

  char* ws = (char*)d_ws;
  size_t off = 0;
  auto alloc = [&](size_t bytes) -> char* {
    char* p = ws + off;
    off += (bytes + 255) & ~(size_t)255;
    return p;
  };

  const size_t DD = (size_t)Dc * Dc;   // 1M elems
  const size_t ND = (size_t)NTc * Dc;  // 4M elems
  const size_t MB8 = 2 * ND;           // 8 MiB
  const size_t M1 = DD;                // 1M elems

  // --- weight region W: 8M bf16 elems (16 MiB), phase-cycled
  bf16* W = (bf16*)alloc(2 * 8 * M1);
  bf16 *wqT = W, *wkT = W + M1, *wvT = W + 2 * M1, *woT = W + 3 * M1;
  bf16 *pqT = W + 4 * M1, *pkT = W + 5 * M1, *pvT = W + 6 * M1, *l0T = W + 7 * M1;
  bf16 *l1T = W + M1;          // staged after wo-GEMM (wkT dead)
  bf16 *l1c = W;               // staged after pred-GEMM (over wqT)
  bf16 *w1T = W + 4 * M1;      // staged after z0-GEMM (pqT..l0T dead)
  bf16 *w2T = W;               // staged after grads (l1c/l1T dead)
  bf16 *w3T = W + 4 * M1;      // staged after ffn1 (w1T dead)

  // --- 5 activation slots, B0..B3 contiguous (s1 spans them at FFN)
  bf16* B0 = (bf16*)alloc(MB8);  // q -> hn2 -> h1r -> h1 -> (s1)
  bf16* B1 = (bf16*)alloc(MB8);  // k -> qlmm -> pred/dp -> (s1)
  bf16* B2 = (bf16*)alloc(MB8);  // v -> kf -> (s1)
  bf16* B3 = (bf16*)alloc(MB8);  // o -> vf -> dz -> (s1)
  bf16* B4 = (bf16*)alloc(MB8);  // hb -> z0 -> hn3
  bf16* s1 = B0;                 // [NT][F] = 32 MiB

  // --- smalls
  float* g0b = (float*)alloc(4 * 1024);
  float* g1b = (float*)alloc(4 * 1024);
  float* lossb = (float*)alloc(256);
  int*   flag  = (int*)alloc(256);
  bf16* n1c = (bf16*)alloc(2 * 1024);
  bf16* n2c = (bf16*)alloc(2 * 1024);
  bf16* n3c = (bf16*)alloc(2 * 1024);
  bf16* bqc = (bf16*)alloc(2 * 1024);
  bf16* bkc = (bf16*)alloc(2 * 1024);
  bf16* bvc = (bf16*)alloc(2 * 1024);
  bf16* b0c = (bf16*)alloc(2 * 1024);
  bf16* b1c = (bf16*)alloc(2 * 1024);

  // --- output regions (fp32)
  float* outX = (float*)d_out;                 // hn(bf16 head), then h2 fp32, then final out fp32
  float* outP = outX + ND;                     // new params (l0w,l0b,l1w,l1b)
  float* outM = outP + (2 * DD + 2048);        // new momenta; hosts g0wF/g1wF pre-update
  float* g0wF = outM;                          // [1M] grad l0_w
  float* g1wF = outM + M1 + 1024;              // [1M] grad l1_w
  bf16*  hn   = (bf16*)outX;                   // bf16 hn in first 8 MiB of outX, dead before h2

  const dim3 tb(32, 8);

  hipMemsetAsync(lossb, 0, sizeof(float), stream);
  hipMemsetAsync(g0b, 0, 4 * 1024, stream);
  hipMemsetAsync(g1b, 0, 4 * 1024, stream);
  k_detect<<<1, 64, 0, stream>>>((const unsigned short*)x, flag);

  // small cvts
  k_cvt<<<1, 256, 0, stream>>>(n1, n1c, 256, flag);
  k_cvt<<<1, 256, 0, stream>>>(n2, n2c, 256, flag);
  k_cvt<<<1, 256, 0, stream>>>(n3, n3c, 256, flag);
  k_cvt<<<1, 256, 0, stream>>>(pqb, bqc, 256, flag);
  k_cvt<<<1, 256, 0, stream>>>(pkb, bkc, 256, flag);
  k_cvt<<<1, 256, 0, stream>>>(pvb, bvc, 256, flag);
  k_cvt<<<1, 256, 0, stream>>>(l0b, b0c, 256, flag);
  k_cvt<<<1, 256, 0, stream>>>(l1b, b1c, 256, flag);

  // phase-1 weight transposes
  k_transpose_dt<<<dim3(32, 32), tb, 0, stream>>>(wq, wqT, Dc, Dc, flag);
  k_transpose_dt<<<dim3(32, 32), tb, 0, stream>>>(wk, wkT, Dc, Dc, flag);
  k_transpose_dt<<<dim3(32, 32), tb, 0, stream>>>(wv, wvT, Dc, Dc, flag);
  k_transpose_dt<<<dim3(32, 32), tb, 0, stream>>>(wo, woT, Dc, Dc, flag);
  k_transpose_dt<<<dim3(32, 32), tb, 0, stream>>>(pqw, pqT, Dc, Mc, flag);
  k_transpose_dt<<<dim3(32, 32), tb, 0, stream>>>(pkw, pkT, Dc, Mc, flag);
  k_transpose_dt<<<dim3(32, 32), tb, 0, stream>>>(pvw, pvT, Dc, Mc, flag);
  k_transpose_dt<<<dim3(32, 32), tb, 0, stream>>>(l0w, l0T, Mc, Mc, flag);

  // ---- attention
  k_rmsnorm_dt<<<NTc, 256, 0, stream>>>(x, n1c, hn, flag);
  k_gemm<EPI_BF16><<<dim3(8, 32), 256, 0, stream>>>(hn, wqT, NTc, Dc, Dc, nullptr, B0, nullptr, nullptr, nullptr, nullptr, nullptr);
  k_gemm<EPI_BF16><<<dim3(8, 32), 256, 0, stream>>>(hn, wkT, NTc, Dc, Dc, nullptr, B1, nullptr, nullptr, nullptr, nullptr, nullptr);
  k_gemm<EPI_BF16><<<dim3(8, 32), 256, 0, stream>>>(hn, wvT, NTc, Dc, Dc, nullptr, B2, nullptr, nullptr, nullptr, nullptr, nullptr);
  k_rope<<<256, 256, 0, stream>>>(B0, B1);
  k_attn<<<1024, 256, 0, stream>>>(B0, B1, B2, B3);
  k_gemm<EPI_RESX_BF16><<<dim3(8, 32), 256, 0, stream>>>(B3, woT, NTc, Dc, Dc, nullptr, B4, nullptr, nullptr, nullptr, x, flag);  // hb -> B4
  k_transpose_dt<<<dim3(32, 32), tb, 0, stream>>>(l1w, l1T, Mc, Mc, flag);

  // ---- LMM forward
  k_rmsnorm_b<<<NTc, 256, 0, stream>>>(B4, n2c, B0);   // hn2 -> B0
  k_gemm<EPI_BIAS_BF16><<<dim3(8, 32), 256, 0, stream>>>(B0, pqT, NTc, Mc, Dc, nullptr, B1, bqc, nullptr, nullptr, nullptr, nullptr);  // qlmm
  k_gemm<EPI_BIAS_BF16><<<dim3(8, 32), 256, 0, stream>>>(B0, pkT, NTc, Mc, Dc, nullptr, B2, bkc, nullptr, nullptr, nullptr, nullptr);  // kf
  k_gemm<EPI_BIAS_BF16><<<dim3(8, 32), 256, 0, stream>>>(B0, pvT, NTc, Mc, Dc, nullptr, B3, bvc, nullptr, nullptr, nullptr, nullptr);  // vf
  k_gemm<EPI_BIAS_RELU_BF16><<<dim3(8, 32), 256, 0, stream>>>(B1, l0T, NTc, Mc, Mc, nullptr, B0, b0c, nullptr, nullptr, nullptr, nullptr);  // h1r
  // h2 = h1r@l1T + l1b + hb -> fp32 in outX (overwrites bf16 hn region; hn is dead)
  k_gemm<EPI_BIAS_RESB_F32><<<dim3(8, 32), 256, 0, stream>>>(B0, l1T, NTc, Mc, Mc, outX, nullptr, b1c, B4, nullptr, nullptr, nullptr);

  // ---- LMM loss fwd/bwd
  k_gemm<EPI_BIAS_BF16><<<dim3(8, 32), 256, 0, stream>>>(B2, l0T, NTc, Mc, Mc, nullptr, B4, b0c, nullptr, nullptr, nullptr, nullptr);  // z0 -> B4
  k_transpose_dt<<<dim3(128, 32), tb, 0, stream>>>(fw1, w1T, Dc, Fc, flag);     // stage w1T (pqT..l0T dead)
  k_relu<<<2048, 256, 0, stream>>>(B4, B0);            // h1 -> B0
  k_gemm<EPI_BIAS_BF16><<<dim3(8, 32), 256, 0, stream>>>(B0, l1T, NTc, Mc, Mc, nullptr, B1, b1c, nullptr, nullptr, nullptr, nullptr);  // pred -> B1
  k_cvt<<<1024, 256, 0, stream>>>(l1w, l1c, (int)(DD / 4), flag);
  k_dpred<<<256, 256, 0, stream>>>(B1, B3, lossb);     // dp in-place over pred (1 atomic/block)
  k_gemm<EPI_DZ_BF16><<<dim3(8, 32), 256, 0, stream>>>(B1, l1c, NTc, Mc, Mc, nullptr, B3, nullptr, B4, nullptr, nullptr, nullptr);     // dz -> B3
  k_gemm_tn<<<dim3(8, 8), 256, 0, stream>>>(B0, B1, NTc, g1wF);   // g1w = h1^T dp (fp32)
  k_gemm_tn<<<dim3(8, 8), 256, 0, stream>>>(B2, B3, NTc, g0wF);   // g0w = kf^T dz (fp32)
  k_colsum<<<dim3(4, 32), 256, 0, stream>>>(B1, g1b, Mc, NTc / 32);
  k_colsum<<<dim3(4, 32), 256, 0, stream>>>(B3, g0b, Mc, NTc / 32);
  k_update_dt<<<8200, 256, 0, stream>>>(l0w, l0b, l1w, l1b, m0w, m0b, m1w, m1b,
                                        g0wF, g0b, g1wF, g1b, lossb, flag, outP, outM);

  // ---- FFN (all B-slots free; h2 fp32 in outX)
  k_transpose_dt<<<dim3(128, 32), tb, 0, stream>>>(fw2, w2T, Dc, Fc, flag);     // stage w2T (l1c/l1T dead)
  k_rmsnorm_f<<<NTc, 256, 0, stream>>>(outX, n3c, B4); // hn3 -> B4
  k_gemm<EPI_BF16><<<dim3(32, 32), 256, 0, stream>>>(B4, w1T, NTc, Fc, Dc, nullptr, s1, nullptr, nullptr, nullptr, nullptr, nullptr);
  k_transpose_dt<<<dim3(32, 128), tb, 0, stream>>>(fw3, w3T, Fc, Dc, flag);     // stage w3T (w1T dead)
  k_gemm<EPI_SILU_BF16><<<dim3(32, 32), 256, 0, stream>>>(B4, w2T, NTc, Fc, Dc, nullptr, s1, nullptr, s1, nullptr, nullptr, nullptr);
  // out = s1@w3T + h2  (fp32 in-place over outX)
  k_gemm<EPI_RESF_F32><<<dim3(8, 32), 256, 0, stream>>>(s1, w3T, NTc, Dc, Fc, outX, nullptr, nullptr, nullptr, outX, nullptr, nullptr);
}

// Round 9
// 1182.733 us; speedup vs baseline: 3.8498x; 1.1334x over previous
//
#include <hip/hip_runtime.h>
#include <cstdint>
#include <cstddef>

typedef __bf16 bf16;
typedef __bf16 bf16x2 __attribute__((ext_vector_type(2)));
typedef __bf16 bf16x4 __attribute__((ext_vector_type(4)));
typedef __bf16 bf16x8 __attribute__((ext_vector_type(8)));
typedef float  f32x4  __attribute__((ext_vector_type(4)));
typedef __attribute__((address_space(1))) unsigned int u32_g;
typedef __attribute__((address_space(3))) unsigned int u32_l;

#define DI __device__ __forceinline__

constexpr int Bc = 2, Sc = 2048, Dc = 1024, Hc = 16, HDc = 64, Fc = 4096, Mc = 1024;
constexpr int NTc = Bc * Sc;  // 4096 tokens

DI void llds16(const bf16* g, bf16* l) {
  __builtin_amdgcn_global_load_lds((const u32_g*)g, (u32_l*)l, 16, 0, 0);
}
DI f32x4 cvt4(bf16x4 a) {
  f32x4 r; r[0] = (float)a[0]; r[1] = (float)a[1]; r[2] = (float)a[2]; r[3] = (float)a[3];
  return r;
}

// ---------------------------------------------------------------- dtype detector (inputs)
__global__ void k_detect(const unsigned short* __restrict__ x, int* __restrict__ flag)
{
  const int tid = threadIdx.x;  // 64
  int cnt = 0;
#pragma unroll
  for (int i = 0; i < 8; i++) {
    unsigned short h = x[tid * 8 + i];
    int e = (h >> 7) & 0xFF;
    if (e < 96 || e > 160) cnt++;
  }
#pragma unroll
  for (int off = 32; off > 0; off >>= 1) cnt += __shfl_down(cnt, off, 64);
  if (tid == 0) *flag = (cnt > 32) ? 1 : 0;
}

// ---------------------------------------------------------------- dtype-aware convert to bf16
__global__ __launch_bounds__(256)
void k_cvt(const void* __restrict__ src, bf16* __restrict__ dst, int n4, const int* __restrict__ flag)
{
  int i = blockIdx.x * 256 + threadIdx.x;
  if (i >= n4) return;
  bf16x4 o;
  if (*flag) {
    f32x4 v = ((const f32x4*)src)[i];
    o[0] = (bf16)v[0]; o[1] = (bf16)v[1]; o[2] = (bf16)v[2]; o[3] = (bf16)v[3];
  } else {
    o = ((const bf16x4*)src)[i];
  }
  ((bf16x4*)dst)[i] = o;
}

// ---------------------------------------------------------------- dtype-aware transpose [R][C] -> bf16 [C][R]
__global__ void k_transpose_dt(const void* __restrict__ src, bf16* __restrict__ dst,
                               int R, int C, const int* __restrict__ flag)
{
  __shared__ bf16 tile[32][33];
  const int c0 = blockIdx.x * 32, r0 = blockIdx.y * 32;
  const int tx = threadIdx.x, ty = threadIdx.y;
  const bool f32 = (*flag != 0);
  for (int i = ty; i < 32; i += 8) {
    size_t idx = (size_t)(r0 + i) * C + (c0 + tx);
    tile[i][tx] = f32 ? (bf16)((const float*)src)[idx] : ((const bf16*)src)[idx];
  }
  __syncthreads();
  for (int i = ty; i < 32; i += 8)
    dst[(size_t)(c0 + i) * R + (r0 + tx)] = tile[tx][i];
}

// ---------------------------------------------------------------- GEMM (NT): C[M][N] = A[M][K] * Bt[N][K]^T
// Epilogue batches aux/res loads per mt-phase into registers BEFORE any store
// of that phase: breaks the compiler's conservative store->load alias ordering
// that serialized the in-place SILU epilogue (926us, MfmaUtil 2.5% in R8).
enum EpiMode { EPI_BF16 = 0, EPI_BIAS_BF16, EPI_BIAS_RELU_BF16, EPI_BIAS_RESB_F32,
               EPI_SILU_BF16, EPI_DZ_BF16, EPI_RESX_BF16, EPI_RESF_F32 };

template <int EPI>
__global__ __launch_bounds__(256)
void k_gemm(const bf16* __restrict__ A, const bf16* __restrict__ Bt,
            int Mr, int Nr, int Kr,
            float* outF, bf16* outB,
            const bf16* __restrict__ bias, const bf16* auxB,
            const float* resF,
            const void* __restrict__ resX, const int* __restrict__ flag)
{
  __shared__ bf16 As[128 * 32];
  __shared__ bf16 Bs[128 * 32];
  const int tid = threadIdx.x;
  const int w = tid >> 6, l = tid & 63;
  const int wr = w >> 1, wc = w & 1;
  const int row0 = blockIdx.y * 128, col0 = blockIdx.x * 128;

  const f32x4 vzero = {0.f, 0.f, 0.f, 0.f};
  f32x4 acc[4][4];
#pragma unroll
  for (int i = 0; i < 4; i++)
#pragma unroll
    for (int j = 0; j < 4; j++) acc[i][j] = vzero;

  const bf16* Ag = A + (size_t)(row0 + w * 16 + (l >> 2)) * Kr + ((l & 3) << 3);
  const bf16* Bg = Bt + (size_t)(col0 + w * 16 + (l >> 2)) * Kr + ((l & 3) << 3);
  bf16* AsW = &As[w * 512];
  bf16* BsW = &Bs[w * 512];
  const size_t rowHop = (size_t)64 * Kr;

  for (int k0 = 0; k0 < Kr; k0 += 32) {
    __syncthreads();
    llds16(Ag + k0, AsW);
    llds16(Ag + rowHop + k0, AsW + 2048);
    llds16(Bg + k0, BsW);
    llds16(Bg + rowHop + k0, BsW + 2048);
    __syncthreads();
    bf16x8 af[4], bfr[4];
#pragma unroll
    for (int mt = 0; mt < 4; mt++)
      af[mt] = *(const bf16x8*)&As[(wr * 64 + mt * 16 + (l & 15)) * 32 + (l >> 4) * 8];
#pragma unroll
    for (int nt = 0; nt < 4; nt++)
      bfr[nt] = *(const bf16x8*)&Bs[(wc * 64 + nt * 16 + (l & 15)) * 32 + (l >> 4) * 8];
#pragma unroll
    for (int mt = 0; mt < 4; mt++)
#pragma unroll
      for (int nt = 0; nt < 4; nt++)
        acc[mt][nt] = __builtin_amdgcn_mfma_f32_16x16x32_bf16(af[mt], bfr[nt], acc[mt][nt], 0, 0, 0);
  }

  const bool f32res = (EPI == EPI_RESX_BF16) ? (*flag != 0) : false;
  // bias preload (before ANY store exists -> fully parallel)
  float biasv[4];
  if (EPI == EPI_BIAS_BF16 || EPI == EPI_BIAS_RELU_BF16 || EPI == EPI_BIAS_RESB_F32) {
#pragma unroll
    for (int nt = 0; nt < 4; nt++)
      biasv[nt] = (float)bias[col0 + wc * 64 + nt * 16 + (l & 15)];
  }
  // C/D layout (verified m89/m91): col = lane&15, row = (lane>>4)*4 + reg
#pragma unroll
  for (int mt = 0; mt < 4; mt++) {
    const int rowb = row0 + wr * 64 + mt * 16 + ((l >> 4) << 2);
    // phase 1: batch-gather aux/res for this mt (16 independent loads)
    float av[4][4];
    if (EPI == EPI_SILU_BF16 || EPI == EPI_DZ_BF16 || EPI == EPI_BIAS_RESB_F32) {
#pragma unroll
      for (int nt = 0; nt < 4; nt++) {
        const int col = col0 + wc * 64 + nt * 16 + (l & 15);
#pragma unroll
        for (int r = 0; r < 4; r++)
          av[nt][r] = (float)auxB[(size_t)(rowb + r) * Nr + col];
      }
    }
    if (EPI == EPI_RESF_F32) {
#pragma unroll
      for (int nt = 0; nt < 4; nt++) {
        const int col = col0 + wc * 64 + nt * 16 + (l & 15);
#pragma unroll
        for (int r = 0; r < 4; r++)
          av[nt][r] = resF[(size_t)(rowb + r) * Nr + col];
      }
    }
    if (EPI == EPI_RESX_BF16) {
#pragma unroll
      for (int nt = 0; nt < 4; nt++) {
        const int col = col0 + wc * 64 + nt * 16 + (l & 15);
#pragma unroll
        for (int r = 0; r < 4; r++) {
          const size_t idx = (size_t)(rowb + r) * Nr + col;
          av[nt][r] = f32res ? ((const float*)resX)[idx] : (float)((const bf16*)resX)[idx];
        }
      }
    }
    // phase 2: compute + store
#pragma unroll
    for (int nt = 0; nt < 4; nt++) {
      const int col = col0 + wc * 64 + nt * 16 + (l & 15);
#pragma unroll
      for (int r = 0; r < 4; r++) {
        const size_t idx = (size_t)(rowb + r) * Nr + col;
        float v = acc[mt][nt][r];
        if (EPI == EPI_BF16) { outB[idx] = (bf16)v; }
        else if (EPI == EPI_BIAS_BF16) { outB[idx] = (bf16)(v + biasv[nt]); }
        else if (EPI == EPI_BIAS_RELU_BF16) { outB[idx] = (bf16)fmaxf(v + biasv[nt], 0.f); }
        else if (EPI == EPI_BIAS_RESB_F32) { outF[idx] = v + biasv[nt] + av[nt][r]; }
        else if (EPI == EPI_SILU_BF16) {
          float s1v = av[nt][r];
          float sl = s1v / (1.f + __expf(-s1v));
          outB[idx] = (bf16)(sl * v);
        }
        else if (EPI == EPI_DZ_BF16) { outB[idx] = (bf16)(av[nt][r] > 0.f ? v : 0.f); }
        else if (EPI == EPI_RESX_BF16) { outB[idx] = (bf16)(v + av[nt][r]); }
        else if (EPI == EPI_RESF_F32) { outF[idx] = v + av[nt][r]; }
      }
    }
  }
}

// ---------------------------------------------------------------- GEMM (TN) split-K: C[i][j] += sum_t X[t][i]*Y[t][j]
// grid (8,8,SPLIT); out must be zero-initialized; fp32 atomicAdd epilogue.
__global__ __launch_bounds__(256)
void k_gemm_tn(const bf16* __restrict__ X, const bf16* __restrict__ Y, int Kt,
               float* __restrict__ out)
{
  __shared__ bf16 As[128 * 36];
  __shared__ bf16 Bs[128 * 36];
  const int tid = threadIdx.x;
  const int w = tid >> 6, l = tid & 63;
  const int wr = w >> 1, wc = w & 1;
  const int row0 = blockIdx.y * 128, col0 = blockIdx.x * 128;
  const int iofs = (tid & 15) * 8;   // 0..120
  const int tp   = (tid >> 4) * 2;   // 0..30

  const f32x4 vzero = {0.f, 0.f, 0.f, 0.f};
  f32x4 acc[4][4];
#pragma unroll
  for (int i = 0; i < 4; i++)
#pragma unroll
    for (int j = 0; j < 4; j++) acc[i][j] = vzero;

  const int chunk = Kt / gridDim.z;
  const int tbeg = blockIdx.z * chunk;

  for (int t0 = tbeg; t0 < tbeg + chunk; t0 += 32) {
    __syncthreads();
    bf16x8 a0 = *(const bf16x8*)&X[(size_t)(t0 + tp) * 1024 + row0 + iofs];
    bf16x8 a1 = *(const bf16x8*)&X[(size_t)(t0 + tp + 1) * 1024 + row0 + iofs];
    bf16x8 b0 = *(const bf16x8*)&Y[(size_t)(t0 + tp) * 1024 + col0 + iofs];
    bf16x8 b1 = *(const bf16x8*)&Y[(size_t)(t0 + tp + 1) * 1024 + col0 + iofs];
#pragma unroll
    for (int e = 0; e < 8; e++) {
      bf16x2 pa; pa[0] = a0[e]; pa[1] = a1[e];
      bf16x2 pb; pb[0] = b0[e]; pb[1] = b1[e];
      *(bf16x2*)&As[(iofs + e) * 36 + tp] = pa;
      *(bf16x2*)&Bs[(iofs + e) * 36 + tp] = pb;
    }
    __syncthreads();
    bf16x8 af[4], bfr[4];
#pragma unroll
    for (int mt = 0; mt < 4; mt++) {
      const int base = (wr * 64 + mt * 16 + (l & 15)) * 36 + (l >> 4) * 8;
      bf16x4 lo = *(const bf16x4*)&As[base];
      bf16x4 hi = *(const bf16x4*)&As[base + 4];
#pragma unroll
      for (int e = 0; e < 4; e++) { af[mt][e] = lo[e]; af[mt][4 + e] = hi[e]; }
    }
#pragma unroll
    for (int nt = 0; nt < 4; nt++) {
      const int base = (wc * 64 + nt * 16 + (l & 15)) * 36 + (l >> 4) * 8;
      bf16x4 lo = *(const bf16x4*)&Bs[base];
      bf16x4 hi = *(const bf16x4*)&Bs[base + 4];
#pragma unroll
      for (int e = 0; e < 4; e++) { bfr[nt][e] = lo[e]; bfr[nt][4 + e] = hi[e]; }
    }
#pragma unroll
    for (int mt = 0; mt < 4; mt++)
#pragma unroll
      for (int nt = 0; nt < 4; nt++)
        acc[mt][nt] = __builtin_amdgcn_mfma_f32_16x16x32_bf16(af[mt], bfr[nt], acc[mt][nt], 0, 0, 0);
  }

#pragma unroll
  for (int mt = 0; mt < 4; mt++) {
    const int rowb = row0 + wr * 64 + mt * 16 + ((l >> 4) << 2);
#pragma unroll
    for (int nt = 0; nt < 4; nt++) {
      const int col = col0 + wc * 64 + nt * 16 + (l & 15);
#pragma unroll
      for (int r = 0; r < 4; r++)
        atomicAdd(&out[(size_t)(rowb + r) * 1024 + col], acc[mt][nt][r]);
    }
  }
}

// ---------------------------------------------------------------- RMSNorm variants
__global__ __launch_bounds__(256)
void k_rmsnorm_dt(const void* __restrict__ x, const bf16* __restrict__ w, bf16* __restrict__ out,
                  const int* __restrict__ flag)
{
  const int row = blockIdx.x;
  const int tid = threadIdx.x;
  f32x4 xv;
  if (*flag) xv = *(const f32x4*)((const float*)x + (size_t)row * Dc + tid * 4);
  else       xv = cvt4(*(const bf16x4*)((const bf16*)x + (size_t)row * Dc + tid * 4));
  float ss = xv[0] * xv[0] + xv[1] * xv[1] + xv[2] * xv[2] + xv[3] * xv[3];
#pragma unroll
  for (int off = 32; off > 0; off >>= 1) ss += __shfl_down(ss, off, 64);
  __shared__ float part[4];
  if ((tid & 63) == 0) part[tid >> 6] = ss;
  __syncthreads();
  float tot = part[0] + part[1] + part[2] + part[3];
  float inv = 1.f / (sqrtf(tot) * 0.03125f + 1e-8f);
  bf16x4 wb = *(const bf16x4*)(w + tid * 4);
  bf16x4 ov;
  ov[0] = (bf16)((float)wb[0] * xv[0] * inv);
  ov[1] = (bf16)((float)wb[1] * xv[1] * inv);
  ov[2] = (bf16)((float)wb[2] * xv[2] * inv);
  ov[3] = (bf16)((float)wb[3] * xv[3] * inv);
  *(bf16x4*)(out + (size_t)row * Dc + tid * 4) = ov;
}

__global__ __launch_bounds__(256)
void k_rmsnorm_b(const bf16* __restrict__ x, const bf16* __restrict__ w, bf16* __restrict__ out)
{
  const int row = blockIdx.x;
  const int tid = threadIdx.x;
  f32x4 xv = cvt4(*(const bf16x4*)(x + (size_t)row * Dc + tid * 4));
  float ss = xv[0] * xv[0] + xv[1] * xv[1] + xv[2] * xv[2] + xv[3] * xv[3];
#pragma unroll
  for (int off = 32; off > 0; off >>= 1) ss += __shfl_down(ss, off, 64);
  __shared__ float part[4];
  if ((tid & 63) == 0) part[tid >> 6] = ss;
  __syncthreads();
  float tot = part[0] + part[1] + part[2] + part[3];
  float inv = 1.f / (sqrtf(tot) * 0.03125f + 1e-8f);
  bf16x4 wb = *(const bf16x4*)(w + tid * 4);
  bf16x4 ov;
  ov[0] = (bf16)((float)wb[0] * xv[0] * inv);
  ov[1] = (bf16)((float)wb[1] * xv[1] * inv);
  ov[2] = (bf16)((float)wb[2] * xv[2] * inv);
  ov[3] = (bf16)((float)wb[3] * xv[3] * inv);
  *(bf16x4*)(out + (size_t)row * Dc + tid * 4) = ov;
}

__global__ __launch_bounds__(256)
void k_rmsnorm_f(const float* __restrict__ x, const bf16* __restrict__ w, bf16* __restrict__ out)
{
  const int row = blockIdx.x;
  const int tid = threadIdx.x;
  f32x4 xv = *(const f32x4*)(x + (size_t)row * Dc + tid * 4);
  float ss = xv[0] * xv[0] + xv[1] * xv[1] + xv[2] * xv[2] + xv[3] * xv[3];
#pragma unroll
  for (int off = 32; off > 0; off >>= 1) ss += __shfl_down(ss, off, 64);
  __shared__ float part[4];
  if ((tid & 63) == 0) part[tid >> 6] = ss;
  __syncthreads();
  float tot = part[0] + part[1] + part[2] + part[3];
  float inv = 1.f / (sqrtf(tot) * 0.03125f + 1e-8f);
  bf16x4 wb = *(const bf16x4*)(w + tid * 4);
  bf16x4 ov;
  ov[0] = (bf16)((float)wb[0] * xv[0] * inv);
  ov[1] = (bf16)((float)wb[1] * xv[1] * inv);
  ov[2] = (bf16)((float)wb[2] * xv[2] * inv);
  ov[3] = (bf16)((float)wb[3] * xv[3] * inv);
  *(bf16x4*)(out + (size_t)row * Dc + tid * 4) = ov;
}

// ---------------------------------------------------------------- RoPE in-place on bf16 q,k
__global__ __launch_bounds__(256)
void k_rope(bf16* __restrict__ q, bf16* __restrict__ kx)
{
  const int idx = blockIdx.x * 256 + threadIdx.x;  // NT*H = 65536
  const int t = idx >> 4, hh = idx & 15;
  const int s = t & (Sc - 1);
  float sn[32], cs[32];
#pragma unroll
  for (int i = 0; i < 32; i++) {
    float f = expf(-(float)i * 0.28782313662425574f);  // ln(10000)/32
    float ang = (float)s * f;
    sn[i] = sinf(ang);
    cs[i] = cosf(ang);
  }
  for (int pass = 0; pass < 2; pass++) {
    bf16* p = (pass ? kx : q) + (size_t)t * Dc + hh * HDc;
    float xb[64], ob[64];
#pragma unroll
    for (int j = 0; j < 16; j++) *(f32x4*)&xb[j * 4] = cvt4(*(const bf16x4*)(p + j * 4));
#pragma unroll
    for (int i = 0; i < 32; i++) {
      float x1 = xb[2 * i], x2 = xb[2 * i + 1];
      ob[i] = x1 * cs[i] - x2 * sn[i];
      ob[32 + i] = x1 * sn[i] + x2 * cs[i];
    }
#pragma unroll
    for (int j = 0; j < 16; j++) {
      bf16x4 o4;
      o4[0] = (bf16)ob[j * 4]; o4[1] = (bf16)ob[j * 4 + 1];
      o4[2] = (bf16)ob[j * 4 + 2]; o4[3] = (bf16)ob[j * 4 + 3];
      *(bf16x4*)(p + j * 4) = o4;
    }
  }
}

// ---------------------------------------------------------------- MFMA flash attention
__global__ __launch_bounds__(256)
void k_attn(const bf16* __restrict__ q, const bf16* __restrict__ kx,
            const bf16* __restrict__ v, bf16* __restrict__ o)
{
  constexpr int PAD = 72;
  __shared__ bf16 Ks[64 * PAD];
  __shared__ bf16 Vt[64 * PAD];        // Vt[d][kk]
  __shared__ bf16 Ps[4][16 * PAD];     // per-wave P buffer

  const int blk = blockIdx.x;
  const int qt = blk & 31;
  const int bh = blk >> 5;
  const int b = bh >> 4, hh = bh & 15;
  const int tid = threadIdx.x;
  const int w = tid >> 6, l = tid & 63;
  const int quad = l >> 4, c = l & 15;

  const int qrow = qt * 64 + w * 16 + c;
  const size_t qbase = ((size_t)(b * Sc + qrow)) * Dc + hh * HDc;
  bf16x8 qf0 = *(const bf16x8*)(q + qbase + quad * 8);
  bf16x8 qf1 = *(const bf16x8*)(q + qbase + 32 + quad * 8);
#pragma unroll
  for (int j = 0; j < 8; j++) {
    qf0[j] = (bf16)((float)qf0[j] * 0.125f);
    qf1[j] = (bf16)((float)qf1[j] * 0.125f);
  }

  const f32x4 vzero = {0.f, 0.f, 0.f, 0.f};
  f32x4 oacc[4];
#pragma unroll
  for (int nt = 0; nt < 4; nt++) oacc[nt] = vzero;
  float mrun[4] = {-3.0e38f, -3.0e38f, -3.0e38f, -3.0e38f};
  float lrun[4] = {0.f, 0.f, 0.f, 0.f};

  const int qrow0 = qt * 64 + w * 16 + quad * 4;

  for (int t0 = 0; t0 <= qt; t0++) {
    const int kk0 = t0 * 64;
    __syncthreads();
    {
      const int trow = tid >> 2;
      const int tpp = tid & 3;
      size_t g = ((size_t)(b * Sc + kk0 + trow)) * Dc + hh * HDc + tpp * 16;
      bf16x8 k0 = *(const bf16x8*)(kx + g);
      bf16x8 k1 = *(const bf16x8*)(kx + g + 8);
      *(bf16x8*)&Ks[trow * PAD + tpp * 16] = k0;
      *(bf16x8*)&Ks[trow * PAD + tpp * 16 + 8] = k1;
      bf16x8 v0 = *(const bf16x8*)(v + g);
      bf16x8 v1 = *(const bf16x8*)(v + g + 8);
#pragma unroll
      for (int j = 0; j < 8; j++) {
        Vt[(tpp * 16 + j) * PAD + trow] = v0[j];
        Vt[(tpp * 16 + 8 + j) * PAD + trow] = v1[j];
      }
    }
    __syncthreads();

    f32x4 sf[4];
#pragma unroll
    for (int nt = 0; nt < 4; nt++) {
      f32x4 a = vzero;
      bf16x8 b0 = *(const bf16x8*)&Ks[(nt * 16 + c) * PAD + quad * 8];
      bf16x8 b1 = *(const bf16x8*)&Ks[(nt * 16 + c) * PAD + 32 + quad * 8];
      a = __builtin_amdgcn_mfma_f32_16x16x32_bf16(qf0, b0, a, 0, 0, 0);
      a = __builtin_amdgcn_mfma_f32_16x16x32_bf16(qf1, b1, a, 0, 0, 0);
      sf[nt] = a;
    }
    if (t0 == qt) {
#pragma unroll
      for (int nt = 0; nt < 4; nt++)
#pragma unroll
        for (int r = 0; r < 4; r++)
          if (kk0 + nt * 16 + c > qrow0 + r) sf[nt][r] = -3.0e38f;
    }

    float mnew[4], alpha[4];
#pragma unroll
    for (int r = 0; r < 4; r++) {
      float mt = fmaxf(fmaxf(sf[0][r], sf[1][r]), fmaxf(sf[2][r], sf[3][r]));
      mt = fmaxf(mt, __shfl_xor(mt, 1, 64));
      mt = fmaxf(mt, __shfl_xor(mt, 2, 64));
      mt = fmaxf(mt, __shfl_xor(mt, 4, 64));
      mt = fmaxf(mt, __shfl_xor(mt, 8, 64));
      mnew[r] = fmaxf(mrun[r], mt);
      alpha[r] = __expf(mrun[r] - mnew[r]);
      mrun[r] = mnew[r];
    }
    float ps[4] = {0.f, 0.f, 0.f, 0.f};
#pragma unroll
    for (int nt = 0; nt < 4; nt++)
#pragma unroll
      for (int r = 0; r < 4; r++) {
        float p = __expf(sf[nt][r] - mnew[r]);
        sf[nt][r] = p;
        ps[r] += p;
      }
#pragma unroll
    for (int r = 0; r < 4; r++) {
      ps[r] += __shfl_xor(ps[r], 1, 64);
      ps[r] += __shfl_xor(ps[r], 2, 64);
      ps[r] += __shfl_xor(ps[r], 4, 64);
      ps[r] += __shfl_xor(ps[r], 8, 64);
      lrun[r] = lrun[r] * alpha[r] + ps[r];
    }
#pragma unroll
    for (int nt = 0; nt < 4; nt++)
#pragma unroll
      for (int r = 0; r < 4; r++) oacc[nt][r] *= alpha[r];

#pragma unroll
    for (int nt = 0; nt < 4; nt++)
#pragma unroll
      for (int r = 0; r < 4; r++)
        Ps[w][(quad * 4 + r) * PAD + nt * 16 + c] = (bf16)sf[nt][r];
    bf16x8 pa0 = *(const bf16x8*)&Ps[w][c * PAD + quad * 8];
    bf16x8 pa1 = *(const bf16x8*)&Ps[w][c * PAD + 32 + quad * 8];

#pragma unroll
    for (int nt = 0; nt < 4; nt++) {
      bf16x8 vb0 = *(const bf16x8*)&Vt[(nt * 16 + c) * PAD + quad * 8];
      bf16x8 vb1 = *(const bf16x8*)&Vt[(nt * 16 + c) * PAD + 32 + quad * 8];
      oacc[nt] = __builtin_amdgcn_mfma_f32_16x16x32_bf16(pa0, vb0, oacc[nt], 0, 0, 0);
      oacc[nt] = __builtin_amdgcn_mfma_f32_16x16x32_bf16(pa1, vb1, oacc[nt], 0, 0, 0);
    }
  }

  float inv[4];
#pragma unroll
  for (int r = 0; r < 4; r++) inv[r] = 1.f / lrun[r];
#pragma unroll
  for (int r = 0; r < 4; r++) {
    const size_t obase = ((size_t)(b * Sc + qrow0 + r)) * Dc + hh * HDc;
#pragma unroll
    for (int nt = 0; nt < 4; nt++)
      o[obase + nt * 16 + c] = (bf16)(oacc[nt][r] * inv[r]);
  }
}

// ---------------------------------------------------------------- elementwise relu (x8)
__global__ __launch_bounds__(256)
void k_relu(const bf16* __restrict__ src, bf16* __restrict__ dst)
{
  int i = blockIdx.x * 256 + threadIdx.x;  // n/8 threads
  bf16x8 v = ((const bf16x8*)src)[i];
  bf16x8 o;
#pragma unroll
  for (int e = 0; e < 8; e++) o[e] = ((float)v[e] > 0.f) ? v[e] : (bf16)0.f;
  ((bf16x8*)dst)[i] = o;
}

// ---------------------------------------------------------------- dp = 2(pred-vf)/M in-place + loss
__global__ __launch_bounds__(256)
void k_dpred(bf16* __restrict__ predDp, const bf16* __restrict__ vf, float* __restrict__ loss)
{
  __shared__ float red[4];
  const int tid = threadIdx.x;
  const size_t n8 = (size_t)NTc * Mc / 8;
  float lacc = 0.f;
  for (size_t i = (size_t)blockIdx.x * 256 + tid; i < n8; i += (size_t)gridDim.x * 256) {
    bf16x8 p8 = ((const bf16x8*)predDp)[i];
    bf16x8 v8 = ((const bf16x8*)vf)[i];
    bf16x8 d8;
#pragma unroll
    for (int e = 0; e < 8; e++) {
      float df = (float)p8[e] - (float)v8[e];
      lacc += df * df;
      d8[e] = (bf16)(df * (2.0f / 1024.0f));
    }
    ((bf16x8*)predDp)[i] = d8;
  }
#pragma unroll
  for (int off = 32; off > 0; off >>= 1) lacc += __shfl_down(lacc, off, 64);
  if ((tid & 63) == 0) red[tid >> 6] = lacc;
  __syncthreads();
  if (tid == 0) atomicAdd(loss, red[0] + red[1] + red[2] + red[3]);
}

// ---------------------------------------------------------------- colsum: out[c] += sum over a row chunk
__global__ __launch_bounds__(256)
void k_colsum(const bf16* __restrict__ X, float* __restrict__ out, int C, int rowsPer)
{
  int c = blockIdx.x * 256 + threadIdx.x;
  int r0 = blockIdx.y * rowsPer;
  float s = 0.f;
#pragma unroll 8
  for (int r = r0; r < r0 + rowsPer; r++) s += (float)X[(size_t)r * C + c];
  atomicAdd(&out[c], s);
}

// ---------------------------------------------------------------- dtype-aware param/momentum update -> fp32 d_out
__global__ __launch_bounds__(256)
void k_update_dt(const void* __restrict__ p0w, const void* __restrict__ p0b,
                 const void* __restrict__ p1w, const void* __restrict__ p1b,
                 const void* __restrict__ m0w, const void* __restrict__ m0b,
                 const void* __restrict__ m1w, const void* __restrict__ m1b,
                 const float* __restrict__ g0wF, const float* __restrict__ g0b,
                 const float* __restrict__ g1wF, const float* __restrict__ g1b,
                 const float* __restrict__ loss, const int* __restrict__ flag,
                 float* __restrict__ outP, float* __restrict__ outM)
{
  const int i = blockIdx.x * 256 + threadIdx.x;  // < 2099200 exactly
  const bool upd = (loss[0] >= 0.1f * 1024.f * 4096.f);  // avg_loss >= THRESH
  const bool f32 = (*flag != 0);
  constexpr int W = 1024 * 1024;
  const void *pp, *pm; int j; float g;
  if (i < W) { pp = p0w; pm = m0w; j = i; g = g0wF[i]; }
  else if (i < W + 1024) { j = i - W; pp = p0b; pm = m0b; g = g0b[j]; }
  else if (i < 2 * W + 1024) { j = i - W - 1024; pp = p1w; pm = m1w; g = g1wF[j]; }
  else { j = i - 2 * W - 1024; pp = p1b; pm = m1b; g = g1b[j]; }
  float p = f32 ? ((const float*)pp)[j] : (float)((const bf16*)pp)[j];
  float m = f32 ? ((const float*)pm)[j] : (float)((const bf16*)pm)[j];
  float nm = 0.9f * m - 0.01f * g;
  float np = 0.99f * p + nm;
  outP[i] = upd ? np : p;
  outM[i] = upd ? nm : m;
}

// ================================================================ host
extern "C" void kernel_launch(void* const* d_in, const int* in_sizes, int n_in,
                              void* d_out, int out_size, void* d_ws, size_t ws_size,
                              hipStream_t stream)
{
  (void)in_sizes; (void)n_in; (void)out_size; (void)ws_size;
  const void* x   = d_in[0];
  const void* wq  = d_in[2];
  const void* wk  = d_in[3];
  const void* wv  = d_in[4];
  const void* wo  = d_in[5];
  const void* n1  = d_in[6];
  const void* n2  = d_in[7];
  const void* n3  = d_in[8];
  const void* fw1 = d_in[9];
  const void* fw2 = d_in[10];
  const void* fw3 = d_in[11];
  const void* pkw = d_in[12];
  const void* pkb = d_in[13];
  const void* pvw = d_in[14];
  const void* pvb = d_in[15];
  const void* pqw = d_in[16];
  const void* pqb = d_in[17];
  const void* l0w = d_in[18];
  const void* l0b = d_in[19];
  const void* l1w = d_in[20];
  const void* l1b = d_in[21];
  const void* m0w = d_in[22];
  const void* m0b = d_in[23];
  const void* m1w = d_in[24];
  const void* m1b = d_in[25];

  char* ws = (char*)d_ws;
  size_t off = 0;
  auto alloc = [&](size_t bytes) -> char* {
    char* p = ws + off;
    off += (bytes + 255) & ~(size_t)255;
    return p;
  };

  const size_t DD = (size_t)Dc * Dc;   // 1M elems
  const size_t ND = (size_t)NTc * Dc;  // 4M elems
  const size_t MB8 = 2 * ND;           // 8 MiB
  const size_t M1 = DD;                // 1M elems

  // --- weight region W: 8M bf16 elems (16 MiB), phase-cycled
  bf16* W = (bf16*)alloc(2 * 8 * M1);
  bf16 *wqT = W, *wkT = W + M1, *wvT = W + 2 * M1, *woT = W + 3 * M1;
  bf16 *pqT = W + 4 * M1, *pkT = W + 5 * M1, *pvT = W + 6 * M1, *l0T = W + 7 * M1;
  bf16 *l1T = W + M1;          // staged after wo-GEMM (wkT dead)
  bf16 *l1c = W;               // staged after pred-GEMM (over wqT)
  bf16 *w1T = W + 4 * M1;      // staged after z0-GEMM (pqT..l0T dead)
  bf16 *w2T = W;               // staged after grads (l1c/l1T dead)
  bf16 *w3T = W + 4 * M1;      // staged after ffn1 (w1T dead)

  // --- 5 activation slots, B0..B3 contiguous (s1 spans them at FFN)
  bf16* B0 = (bf16*)alloc(MB8);  // q -> hn2 -> h1r -> h1 -> (s1)
  bf16* B1 = (bf16*)alloc(MB8);  // k -> qlmm -> pred/dp -> (s1)
  bf16* B2 = (bf16*)alloc(MB8);  // v -> kf -> (s1)
  bf16* B3 = (bf16*)alloc(MB8);  // o -> vf -> dz -> (s1)
  bf16* B4 = (bf16*)alloc(MB8);  // hb -> z0 -> hn3
  bf16* s1 = B0;                 // [NT][F] = 32 MiB

  // --- smalls
  float* g0b = (float*)alloc(4 * 1024);
  float* g1b = (float*)alloc(4 * 1024);
  float* lossb = (float*)alloc(256);
  int*   flag  = (int*)alloc(256);
  bf16* n1c = (bf16*)alloc(2 * 1024);
  bf16* n2c = (bf16*)alloc(2 * 1024);
  bf16* n3c = (bf16*)alloc(2 * 1024);
  bf16* bqc = (bf16*)alloc(2 * 1024);
  bf16* bkc = (bf16*)alloc(2 * 1024);
  bf16* bvc = (bf16*)alloc(2 * 1024);
  bf16* b0c = (bf16*)alloc(2 * 1024);
  bf16* b1c = (bf16*)alloc(2 * 1024);

  // --- output regions (fp32)
  float* outX = (float*)d_out;                 // hn(bf16 head), then h2 fp32, then final out fp32
  float* outP = outX + ND;                     // new params (l0w,l0b,l1w,l1b)
  float* outM = outP + (2 * DD + 2048);        // new momenta; hosts g0wF/g1wF pre-update
  float* g0wF = outM;                          // [1M] grad l0_w
  float* g1wF = outM + M1 + 1024;              // [1M] grad l1_w
  bf16*  hn   = (bf16*)outX;                   // bf16 hn in first 8 MiB of outX, dead before h2

  const dim3 tb(32, 8);

  hipMemsetAsync(lossb, 0, sizeof(float), stream);
  hipMemsetAsync(g0b, 0, 4 * 1024, stream);
  hipMemsetAsync(g1b, 0, 4 * 1024, stream);
  hipMemsetAsync(outM, 0, (2 * M1 + 2048) * sizeof(float), stream);  // zero g0wF/g1wF for split-K atomics
  k_detect<<<1, 64, 0, stream>>>((const unsigned short*)x, flag);

  // small cvts
  k_cvt<<<1, 256, 0, stream>>>(n1, n1c, 256, flag);
  k_cvt<<<1, 256, 0, stream>>>(n2, n2c, 256, flag);
  k_cvt<<<1, 256, 0, stream>>>(n3, n3c, 256, flag);
  k_cvt<<<1, 256, 0, stream>>>(pqb, bqc, 256, flag);
  k_cvt<<<1, 256, 0, stream>>>(pkb, bkc, 256, flag);
  k_cvt<<<1, 256, 0, stream>>>(pvb, bvc, 256, flag);
  k_cvt<<<1, 256, 0, stream>>>(l0b, b0c, 256, flag);
  k_cvt<<<1, 256, 0, stream>>>(l1b, b1c, 256, flag);

  // phase-1 weight transposes
  k_transpose_dt<<<dim3(32, 32), tb, 0, stream>>>(wq, wqT, Dc, Dc, flag);
  k_transpose_dt<<<dim3(32, 32), tb, 0, stream>>>(wk, wkT, Dc, Dc, flag);
  k_transpose_dt<<<dim3(32, 32), tb, 0, stream>>>(wv, wvT, Dc, Dc, flag);
  k_transpose_dt<<<dim3(32, 32), tb, 0, stream>>>(wo, woT, Dc, Dc, flag);
  k_transpose_dt<<<dim3(32, 32), tb, 0, stream>>>(pqw, pqT, Dc, Mc, flag);
  k_transpose_dt<<<dim3(32, 32), tb, 0, stream>>>(pkw, pkT, Dc, Mc, flag);
  k_transpose_dt<<<dim3(32, 32), tb, 0, stream>>>(pvw, pvT, Dc, Mc, flag);
  k_transpose_dt<<<dim3(32, 32), tb, 0, stream>>>(l0w, l0T, Mc, Mc, flag);

  // ---- attention
  k_rmsnorm_dt<<<NTc, 256, 0, stream>>>(x, n1c, hn, flag);
  k_gemm<EPI_BF16><<<dim3(8, 32), 256, 0, stream>>>(hn, wqT, NTc, Dc, Dc, nullptr, B0, nullptr, nullptr, nullptr, nullptr, nullptr);
  k_gemm<EPI_BF16><<<dim3(8, 32), 256, 0, stream>>>(hn, wkT, NTc, Dc, Dc, nullptr, B1, nullptr, nullptr, nullptr, nullptr, nullptr);
  k_gemm<EPI_BF16><<<dim3(8, 32), 256, 0, stream>>>(hn, wvT, NTc, Dc, Dc, nullptr, B2, nullptr, nullptr, nullptr, nullptr, nullptr);
  k_rope<<<256, 256, 0, stream>>>(B0, B1);
  k_attn<<<1024, 256, 0, stream>>>(B0, B1, B2, B3);
  k_gemm<EPI_RESX_BF16><<<dim3(8, 32), 256, 0, stream>>>(B3, woT, NTc, Dc, Dc, nullptr, B4, nullptr, nullptr, nullptr, x, flag);  // hb -> B4
  k_transpose_dt<<<dim3(32, 32), tb, 0, stream>>>(l1w, l1T, Mc, Mc, flag);

  // ---- LMM forward
  k_rmsnorm_b<<<NTc, 256, 0, stream>>>(B4, n2c, B0);   // hn2 -> B0
  k_gemm<EPI_BIAS_BF16><<<dim3(8, 32), 256, 0, stream>>>(B0, pqT, NTc, Mc, Dc, nullptr, B1, bqc, nullptr, nullptr, nullptr, nullptr);  // qlmm
  k_gemm<EPI_BIAS_BF16><<<dim3(8, 32), 256, 0, stream>>>(B0, pkT, NTc, Mc, Dc, nullptr, B2, bkc, nullptr, nullptr, nullptr, nullptr);  // kf
  k_gemm<EPI_BIAS_BF16><<<dim3(8, 32), 256, 0, stream>>>(B0, pvT, NTc, Mc, Dc, nullptr, B3, bvc, nullptr, nullptr, nullptr, nullptr);  // vf
  k_gemm<EPI_BIAS_RELU_BF16><<<dim3(8, 32), 256, 0, stream>>>(B1, l0T, NTc, Mc, Mc, nullptr, B0, b0c, nullptr, nullptr, nullptr, nullptr);  // h1r
  // h2 = h1r@l1T + l1b + hb -> fp32 in outX (overwrites bf16 hn region; hn is dead)
  k_gemm<EPI_BIAS_RESB_F32><<<dim3(8, 32), 256, 0, stream>>>(B0, l1T, NTc, Mc, Mc, outX, nullptr, b1c, B4, nullptr, nullptr, nullptr);

  // ---- LMM loss fwd/bwd
  k_gemm<EPI_BIAS_BF16><<<dim3(8, 32), 256, 0, stream>>>(B2, l0T, NTc, Mc, Mc, nullptr, B4, b0c, nullptr, nullptr, nullptr, nullptr);  // z0 -> B4
  k_transpose_dt<<<dim3(128, 32), tb, 0, stream>>>(fw1, w1T, Dc, Fc, flag);     // stage w1T (pqT..l0T dead)
  k_relu<<<2048, 256, 0, stream>>>(B4, B0);            // h1 -> B0
  k_gemm<EPI_BIAS_BF16><<<dim3(8, 32), 256, 0, stream>>>(B0, l1T, NTc, Mc, Mc, nullptr, B1, b1c, nullptr, nullptr, nullptr, nullptr);  // pred -> B1
  k_cvt<<<1024, 256, 0, stream>>>(l1w, l1c, (int)(DD / 4), flag);
  k_dpred<<<256, 256, 0, stream>>>(B1, B3, lossb);     // dp in-place over pred (1 atomic/block)
  k_gemm<EPI_DZ_BF16><<<dim3(8, 32), 256, 0, stream>>>(B1, l1c, NTc, Mc, Mc, nullptr, B3, nullptr, B4, nullptr, nullptr, nullptr);     // dz -> B3
  k_gemm_tn<<<dim3(8, 8, 8), 256, 0, stream>>>(B0, B1, NTc, g1wF);   // g1w = h1^T dp (split-K atomic)
  k_gemm_tn<<<dim3(8, 8, 8), 256, 0, stream>>>(B2, B3, NTc, g0wF);   // g0w = kf^T dz (split-K atomic)
  k_colsum<<<dim3(4, 32), 256, 0, stream>>>(B1, g1b, Mc, NTc / 32);
  k_colsum<<<dim3(4, 32), 256, 0, stream>>>(B3, g0b, Mc, NTc / 32);
  k_update_dt<<<8200, 256, 0, stream>>>(l0w, l0b, l1w, l1b, m0w, m0b, m1w, m1b,
                                        g0wF, g0b, g1wF, g1b, lossb, flag, outP, outM);

  // ---- FFN (all B-slots free; h2 fp32 in outX)
  k_transpose_dt<<<dim3(128, 32), tb, 0, stream>>>(fw2, w2T, Dc, Fc, flag);     // stage w2T (l1c/l1T dead)
  k_rmsnorm_f<<<NTc, 256, 0, stream>>>(outX, n3c, B4); // hn3 -> B4
  k_gemm<EPI_BF16><<<dim3(32, 32), 256, 0, stream>>>(B4, w1T, NTc, Fc, Dc, nullptr, s1, nullptr, nullptr, nullptr, nullptr, nullptr);
  k_transpose_dt<<<dim3(32, 128), tb, 0, stream>>>(fw3, w3T, Fc, Dc, flag);     // stage w3T (w1T dead)
  k_gemm<EPI_SILU_BF16><<<dim3(32, 32), 256, 0, stream>>>(B4, w2T, NTc, Fc, Dc, nullptr, s1, nullptr, s1, nullptr, nullptr, nullptr);
  // out = s1@w3T + h2  (fp32 in-place over outX)
  k_gemm<EPI_RESF_F32><<<dim3(8, 32), 256, 0, stream>>>(s1, w3T, NTc, Dc, Fc, outX, nullptr, nullptr, nullptr, outX, nullptr, nullptr);
}